// Round 7
// baseline (638.734 us; speedup 1.0000x reference)
//
#include <hip/hip_runtime.h>
#include <hip/hip_bf16.h>
#include <cstdint>
#include <cstddef>

constexpr int TPB = 256;
constexpr int SCAN_B = 1024;
constexpr int BSHIFT = 7;       // 128 nodes per bucket
using bf16x8 = __attribute__((ext_vector_type(8))) short;
using f32x4  = __attribute__((ext_vector_type(4))) float;

static inline int cdiv(int a, int b) { return (a + b - 1) / b; }

__device__ __forceinline__ float bf2f(short u) {
  return __uint_as_float(((unsigned int)(unsigned short)u) << 16);
}
__device__ __forceinline__ short f2bf(float f) {  // RNE
  unsigned int u = __float_as_uint(f);
  return (short)((u + 0x7FFF + ((u >> 16) & 1)) >> 16);
}

__global__ void zero_int_kernel(int* p, int n) {
  int i = blockIdx.x * TPB + threadIdx.x;
  if (i < n) p[i] = 0;
}

// node-degree hist + (bucket,shard) hist in one pass.
// shard(e) = (e>>8)&7 matches bucket_scatter's blockIdx&7 (256 edges/block).
__global__ void hist2_kernel(const int* __restrict__ dst, int* counts, int* bh, int e_cnt) {
  int e = blockIdx.x * TPB + threadIdx.x;
  if (e >= e_cnt) return;
  int d = dst[e];
  atomicAdd(&counts[d], 1);
  int sh = (e >> 8) & 7;
  atomicAdd(&bh[((d >> BSHIFT) << 3) | sh], 1);
}

__global__ void dinv_kernel(const int* __restrict__ counts, float* dinv, int n) {
  int i = blockIdx.x * TPB + threadIdx.x;
  if (i < n) dinv[i] = rsqrtf((float)counts[i] + 1.0f);  // +1 self-loop
}

// multi-block scan, phase 1: per-block exclusive scan + block sums
__global__ __launch_bounds__(SCAN_B)
void scan_block_kernel(const int* __restrict__ counts, int* __restrict__ rowptr,
                       int* __restrict__ bsum, int n) {
  __shared__ int wsum[16];
  const int tid = threadIdx.x;
  const int i = blockIdx.x * SCAN_B + tid;
  const int lane = tid & 63;
  const int w = tid >> 6;
  int v = (i < n) ? counts[i] : 0;
  int s = v;
  #pragma unroll
  for (int off = 1; off < 64; off <<= 1) {
    int t = __shfl_up(s, off, 64);
    if (lane >= off) s += t;
  }
  if (lane == 63) wsum[w] = s;
  __syncthreads();
  if (tid < 16) {
    int ws_ = wsum[tid];
    #pragma unroll
    for (int off = 1; off < 16; off <<= 1) {
      int t = __shfl_up(ws_, off, 64);
      if (tid >= off) ws_ += t;
    }
    wsum[tid] = ws_;
  }
  __syncthreads();
  int woff = (w == 0) ? 0 : wsum[w - 1];
  if (i < n) rowptr[i] = woff + s - v;
  if (tid == SCAN_B - 1) bsum[blockIdx.x] = woff + s;
}

// phase 2: exclusive scan of block sums (nb <= 128), one block of 128
__global__ void scan_carry_kernel(int* bsum, int nb) {
  __shared__ int w0;
  int tid = threadIdx.x;
  int v = (tid < nb) ? bsum[tid] : 0;
  int s = v;
  #pragma unroll
  for (int off = 1; off < 64; off <<= 1) {
    int t = __shfl_up(s, off, 64);
    if ((tid & 63) >= off) s += t;
  }
  if (tid == 63) w0 = s;
  __syncthreads();
  int incl = s + ((tid >= 64) ? w0 : 0);
  if (tid < nb) bsum[tid] = incl - v;
}

// phase 3: add block offsets (+ write total at [n])
__global__ void scan_add_kernel(int* rowptr, const int* __restrict__ bsum, int n, int total) {
  int i = blockIdx.x * TPB + threadIdx.x;
  if (i < n) rowptr[i] += bsum[i / SCAN_B];
  if (i == 0) rowptr[n] = total;
}

// pass 1 of sort: edges -> bucket/shard-partitioned packed buffer.
// block B (256 edges) uses shard B&7; entry = (src<<BSHIFT)|(dst&(2^BSHIFT-1)).
__global__ void bucket_scatter_kernel(const int* __restrict__ src, const int* __restrict__ dst,
                                      const int* __restrict__ boff, int* bcur,
                                      unsigned int* __restrict__ ebuf, int e_cnt) {
  int e = blockIdx.x * TPB + threadIdx.x;
  if (e >= e_cnt) return;
  int d = dst[e];
  int sh = blockIdx.x & 7;
  int slot = ((d >> BSHIFT) << 3) | sh;
  int pos = boff[slot] + atomicAdd(&bcur[slot], 1);
  ebuf[pos] = ((unsigned int)src[e] << BSHIFT) | (unsigned int)(d & ((1 << BSHIFT) - 1));
}

// pass 2: one block per bucket; bucket's csr window + cursors are block-private.
__global__ void final_scatter_kernel(const unsigned int* __restrict__ ebuf,
                                     const int* __restrict__ boff,
                                     const int* __restrict__ rowptr, int* cursor,
                                     int* __restrict__ csr_src, int n_bucket) {
  int b = blockIdx.x;
  int beg = boff[b << 3];
  int end = boff[(b + 1) << 3];
  int base = b << BSHIFT;
  for (int i = beg + threadIdx.x; i < end; i += TPB) {
    unsigned int p = ebuf[i];
    int d = base | (int)(p & ((1u << BSHIFT) - 1));
    int s = (int)(p >> BSHIFT);
    int pos = rowptr[d] + atomicAdd(&cursor[d], 1);
    csr_src[pos] = s;
  }
}

// pad x [n,7] -> x8 [n,8] (8th = 0)
__global__ void pad_x8_kernel(const float* __restrict__ x, float* __restrict__ x8, int n) {
  int i = blockIdx.x * TPB + threadIdx.x;
  if (i >= n * 8) return;
  int node = i >> 3, f = i & 7;
  x8[i] = (f < 7) ? x[node * 7 + f] : 0.0f;
}

// pad W1 [7,128] -> W1p [8,128]
__global__ void pad_w1_kernel(const float* __restrict__ W1, float* __restrict__ W1p) {
  int i = blockIdx.x * TPB + threadIdx.x;
  if (i < 8 * 128) W1p[i] = (i < 7 * 128) ? W1[i] : 0.0f;
}

// aggx = A_hat @ x8 : 8 lanes per node (one float each)
__global__ __launch_bounds__(256)
void agg_x_kernel(const int* __restrict__ rowptr, const int* __restrict__ csr_src,
                  const float* __restrict__ dinv, const float* __restrict__ x8,
                  float* __restrict__ aggx, int n_nodes) {
  int gid = blockIdx.x * TPB + threadIdx.x;
  int node = gid >> 3;
  int f = gid & 7;
  if (node >= n_nodes) return;
  float dn = dinv[node];
  float acc = x8[(size_t)node * 8 + f] * dn * dn;
  int beg = rowptr[node], end = rowptr[node + 1];
  for (int i = beg; i < end; ++i) {
    int s = csr_src[i];
    acc = fmaf(x8[(size_t)s * 8 + f], dinv[s] * dn, acc);
  }
  aggx[(size_t)node * 8 + f] = acc;
}

// g1 = A_hat @ h1 with h1s prescaled by dinv (bf16):
// g1[n] = dinv[n] * ( h1s[n] + sum_{s in N(n)} h1s[s] ); 4 edges/wave
__global__ __launch_bounds__(256)
void gather4_kernel(const int* __restrict__ rowptr, const int* __restrict__ csr_src,
                    const float* __restrict__ dinv, const uint4* __restrict__ h1s,
                    uint4* __restrict__ g1, int n_nodes) {
  int wid = (blockIdx.x * TPB + threadIdx.x) >> 6;
  if (wid >= n_nodes) return;
  int lane = threadIdx.x & 63;
  int qtr = lane >> 4;
  int l = lane & 15;
  float acc[8];
  #pragma unroll
  for (int j = 0; j < 8; ++j) acc[j] = 0.0f;
  auto addv = [&](uint4 v) {
    unsigned int u[4] = {v.x, v.y, v.z, v.w};
    #pragma unroll
    for (int p = 0; p < 4; ++p) {
      acc[2 * p]     += __uint_as_float(u[p] << 16);
      acc[2 * p + 1] += __uint_as_float(u[p] & 0xffff0000u);
    }
  };
  if (qtr == 0) addv(h1s[(size_t)wid * 16 + l]);  // self term
  int beg = rowptr[wid], end = rowptr[wid + 1];
  int i = beg + qtr;
  for (; i + 4 < end; i += 8) {
    int s0 = csr_src[i];
    int s1 = csr_src[i + 4];
    uint4 v0 = h1s[(size_t)s0 * 16 + l];
    uint4 v1 = h1s[(size_t)s1 * 16 + l];
    addv(v0);
    addv(v1);
  }
  if (i < end) addv(h1s[(size_t)csr_src[i] * 16 + l]);
  #pragma unroll
  for (int j = 0; j < 8; ++j) {
    acc[j] += __shfl_xor(acc[j], 16, 64);
    acc[j] += __shfl_xor(acc[j], 32, 64);
  }
  if (qtr == 0) {
    float dn = dinv[wid];
    unsigned int w[4];
    #pragma unroll
    for (int p = 0; p < 4; ++p) {
      unsigned int lo = (unsigned int)(unsigned short)f2bf(acc[2 * p] * dn);
      unsigned int hi = (unsigned int)(unsigned short)f2bf(acc[2 * p + 1] * dn);
      w[p] = lo | (hi << 16);
    }
    uint4 o; o.x = w[0]; o.y = w[1]; o.z = w[2]; o.w = w[3];
    g1[(size_t)wid * 16 + l] = o;
  }
}

// Register-tiled SGEMM: out[row][j] = sum_k in[row][k]*W[k][j] (+bias)(+relu)
// OB: bf16 output; IB: bf16 input; SC: multiply output by scale[row] (after relu)
template<int K, int CO, bool OB, bool IB, bool SC>
__global__ __launch_bounds__(256)
void mm_tiled(const void* __restrict__ inv, const float* __restrict__ W,
              const float* __restrict__ bias, const float* __restrict__ scale,
              void* __restrict__ outv, int n_rows, int do_relu) {
  constexpr int BM = 64;
  constexpr int BK = (K % 32 == 0) ? 32 : K;
  constexpr int SS = BK + 1 + (BK & 1);
  constexpr int TM = 4;
  constexpr int TN = CO / 16;
  __shared__ float s_in[BM][SS];
  __shared__ float s_w[BK][CO];
  const int tid = threadIdx.x;
  const int base = blockIdx.x * BM;
  const int tr = tid >> 4;
  const int tc = tid & 15;

  float acc[TM][TN];
  #pragma unroll
  for (int m = 0; m < TM; ++m)
    #pragma unroll
    for (int n = 0; n < TN; ++n) acc[m][n] = 0.0f;

  for (int kb = 0; kb < K; kb += BK) {
    if constexpr (IB) {
      const unsigned short* inb = (const unsigned short*)inv;
      constexpr int C4 = BK / 4;
      constexpr int F4 = BM * C4;
      #pragma unroll
      for (int t = tid; t < F4; t += TPB) {
        int r = t / C4, c4 = t % C4;
        int row = base + r;
        uint2 v = make_uint2(0u, 0u);
        if (row < n_rows) v = *(const uint2*)(inb + (size_t)row * K + kb + c4 * 4);
        s_in[r][c4 * 4 + 0] = __uint_as_float(v.x << 16);
        s_in[r][c4 * 4 + 1] = __uint_as_float(v.x & 0xffff0000u);
        s_in[r][c4 * 4 + 2] = __uint_as_float(v.y << 16);
        s_in[r][c4 * 4 + 3] = __uint_as_float(v.y & 0xffff0000u);
      }
    } else if constexpr (BK % 4 == 0) {
      const float* in = (const float*)inv;
      constexpr int F4 = BM * (BK / 4);
      #pragma unroll
      for (int t = tid; t < F4; t += TPB) {
        int r = t / (BK / 4), c4 = t % (BK / 4);
        int row = base + r;
        float4 v = make_float4(0.f, 0.f, 0.f, 0.f);
        if (row < n_rows) v = *(const float4*)(in + (size_t)row * K + kb + c4 * 4);
        s_in[r][c4 * 4 + 0] = v.x;
        s_in[r][c4 * 4 + 1] = v.y;
        s_in[r][c4 * 4 + 2] = v.z;
        s_in[r][c4 * 4 + 3] = v.w;
      }
    } else {
      const float* in = (const float*)inv;
      for (int t = tid; t < BM * BK; t += TPB) {
        int r = t / BK, c = t % BK;
        int row = base + r;
        s_in[r][c] = (row < n_rows) ? in[(size_t)row * K + kb + c] : 0.0f;
      }
    }
    {
      constexpr int WF4 = BK * CO / 4;
      #pragma unroll
      for (int t = tid; t < WF4; t += TPB)
        *(float4*)(&s_w[0][0] + t * 4) = *(const float4*)(W + (size_t)kb * CO + t * 4);
    }
    __syncthreads();

    #pragma unroll
    for (int kk = 0; kk < BK; ++kk) {
      float a[TM], b[TN];
      #pragma unroll
      for (int m = 0; m < TM; ++m) a[m] = s_in[tr * TM + m][kk];
      #pragma unroll
      for (int n = 0; n < TN; ++n) b[n] = s_w[kk][tc + 16 * n];
      #pragma unroll
      for (int m = 0; m < TM; ++m)
        #pragma unroll
        for (int n = 0; n < TN; ++n) acc[m][n] = fmaf(a[m], b[n], acc[m][n]);
    }
    __syncthreads();
  }

  #pragma unroll
  for (int m = 0; m < TM; ++m) {
    int row = base + tr * TM + m;
    if (row < n_rows) {
      float sc = 1.0f;
      if constexpr (SC) sc = scale[row];
      #pragma unroll
      for (int n = 0; n < TN; ++n) {
        int j = tc + 16 * n;
        float v = acc[m][n] + (bias ? bias[j] : 0.0f);
        if (do_relu) v = fmaxf(v, 0.0f);
        if constexpr (SC) v *= sc;
        if constexpr (OB)
          ((unsigned short*)outv)[(size_t)row * CO + j] = (unsigned short)f2bf(v);
        else
          ((float*)outv)[(size_t)row * CO + j] = v;
      }
    }
  }
}

// MFMA decoder: 16 queries per wave-tile. (layouts guide-verified)
__global__ __launch_bounds__(256)
void decoder_mfma_kernel(const int* __restrict__ qsrc, const int* __restrict__ qdst,
                         const unsigned short* __restrict__ atab,
                         const unsigned short* __restrict__ btab,
                         const float* __restrict__ Wd2, const float* __restrict__ bd2,
                         const float* __restrict__ Wd3, const float* __restrict__ bd3,
                         float* __restrict__ out, int n_query) {
  const int lane = threadIdx.x & 63;
  const int col = lane & 15;
  const int sub = lane >> 4;

  bf16x8 bfrag[4][4];
  #pragma unroll
  for (int ks = 0; ks < 4; ++ks)
    #pragma unroll
    for (int nt = 0; nt < 4; ++nt) {
      bf16x8 f;
      #pragma unroll
      for (int j = 0; j < 8; ++j) {
        int k = ks * 32 + sub * 8 + j;
        int n = nt * 16 + col;
        f[j] = f2bf(Wd2[k * 64 + n]);
      }
      bfrag[ks][nt] = f;
    }
  float bd2v[4], wd3v[4];
  #pragma unroll
  for (int nt = 0; nt < 4; ++nt) {
    bd2v[nt] = bd2[nt * 16 + col];
    wd3v[nt] = Wd3[nt * 16 + col];
  }
  const float bd3s = bd3[0];

  int wave = (blockIdx.x * TPB + threadIdx.x) >> 6;
  int nwaves = gridDim.x * (TPB / 64);
  int ntiles = (n_query + 15) >> 4;
  for (int t = wave; t < ntiles; t += nwaves) {
    int qb = t << 4;
    int q = qb + col;
    if (q >= n_query) q = n_query - 1;
    int si = qsrc[q], di = qdst[q];
    const bf16x8* ar = (const bf16x8*)(atab + (size_t)si * 128);
    const bf16x8* br = (const bf16x8*)(btab + (size_t)di * 128);
    bf16x8 afrag[4];
    #pragma unroll
    for (int ks = 0; ks < 4; ++ks) {
      bf16x8 av = ar[ks * 4 + sub];
      bf16x8 bv = br[ks * 4 + sub];
      bf16x8 d;
      #pragma unroll
      for (int j = 0; j < 8; ++j)
        d[j] = f2bf(fmaxf(bf2f(av[j]) + bf2f(bv[j]), 0.0f));  // d1 = relu(a+b)
      afrag[ks] = d;
    }
    f32x4 acc[4];
    #pragma unroll
    for (int nt = 0; nt < 4; ++nt) acc[nt] = {0.f, 0.f, 0.f, 0.f};
    #pragma unroll
    for (int ks = 0; ks < 4; ++ks)
      #pragma unroll
      for (int nt = 0; nt < 4; ++nt)
        acc[nt] = __builtin_amdgcn_mfma_f32_16x16x32_bf16(afrag[ks], bfrag[ks][nt], acc[nt], 0, 0, 0);
    float part[4] = {0.f, 0.f, 0.f, 0.f};
    #pragma unroll
    for (int nt = 0; nt < 4; ++nt)
      #pragma unroll
      for (int r = 0; r < 4; ++r) {
        float v = fmaxf(acc[nt][r] + bd2v[nt], 0.0f);
        part[r] = fmaf(v, wd3v[nt], part[r]);
      }
    #pragma unroll
    for (int off = 1; off < 16; off <<= 1)
      #pragma unroll
      for (int r = 0; r < 4; ++r) part[r] += __shfl_xor(part[r], off, 64);
    if (col == 0) {
      int row0 = qb + sub * 4;
      #pragma unroll
      for (int r = 0; r < 4; ++r) {
        int qq = row0 + r;
        if (qq < n_query) out[qq] = 1.0f / (1.0f + __expf(-(part[r] + bd3s)));
      }
    }
  }
}

extern "C" void kernel_launch(void* const* d_in, const int* in_sizes, int n_in,
                              void* d_out, int out_size, void* d_ws, size_t ws_size,
                              hipStream_t stream) {
  const float* x    = (const float*)d_in[0];
  const int*   ei   = (const int*)d_in[1];
  const int*   qe   = (const int*)d_in[2];
  const float* W1   = (const float*)d_in[3];
  const float* b1   = (const float*)d_in[4];
  const float* W2   = (const float*)d_in[5];
  const float* b2   = (const float*)d_in[6];
  const float* Wfc  = (const float*)d_in[7];
  const float* bfc  = (const float*)d_in[8];
  const float* Wd1  = (const float*)d_in[9];
  const float* bd1  = (const float*)d_in[10];
  const float* Wd2  = (const float*)d_in[11];
  const float* bd2  = (const float*)d_in[12];
  const float* Wd3  = (const float*)d_in[13];
  const float* bd3  = (const float*)d_in[14];
  float* out = (float*)d_out;

  const int n_nodes = in_sizes[0] / 7;
  const int n_edges = in_sizes[1] / 2;
  const int n_query = in_sizes[2] / 2;
  const int* e_src = ei;
  const int* e_dst = ei + n_edges;
  const int* q_src = qe;
  const int* q_dst = qe + n_query;

  const int n_bucket = cdiv(n_nodes, 1 << BSHIFT);
  const int n_slot = n_bucket * 8;   // (bucket, shard) slots

  // ---- workspace layout ----
  char* wp = (char*)d_ws;
  auto take = [&](size_t bytes) { char* p = wp; wp += (bytes + 255) & ~size_t(255); return p; };
  float* dinv    = (float*)take((size_t)n_nodes * 4);
  int*   counts  = (int*)  take((size_t)n_nodes * 4);   // reused as cursor
  int*   rowptr  = (int*)  take((size_t)(n_nodes + 1) * 4);
  int*   bsum    = (int*)  take(512 * 4);
  int*   bh      = (int*)  take((size_t)(n_slot + 1) * 4);  // (bucket,shard) hist; then cursors
  int*   boff    = (int*)  take((size_t)(n_slot + 1) * 4);
  unsigned int* ebuf = (unsigned int*)take((size_t)n_edges * 4);
  int*   csr_src = (int*)  take((size_t)n_edges * 4);
  float* x8      = (float*)take((size_t)n_nodes * 8 * 4);
  float* aggx    = (float*)take((size_t)n_nodes * 8 * 4);
  float* W1p     = (float*)take(8 * 128 * 4);
  float* bufP    = (float*)take((size_t)n_nodes * 128 * 4);
  float* bufQ    = (float*)take((size_t)n_nodes * 128 * 4);
  float* bufR    = (float*)take((size_t)n_nodes * 64 * 4);

  const int mm_blocks = cdiv(n_nodes, 64);
  const int node_blocks = cdiv(n_nodes, TPB);
  const int edge_blocks = cdiv(n_edges, TPB);
  const int scan_blocks = cdiv(n_nodes, SCAN_B);
  const int bscan_blocks = cdiv(n_slot, SCAN_B);

  // ---- CSR build: hist -> scans -> 2-pass locality-sharded counting sort ----
  zero_int_kernel<<<node_blocks, TPB, 0, stream>>>(counts, n_nodes);
  zero_int_kernel<<<cdiv(n_slot, TPB), TPB, 0, stream>>>(bh, n_slot);
  hist2_kernel<<<edge_blocks, TPB, 0, stream>>>(e_dst, counts, bh, n_edges);
  dinv_kernel<<<node_blocks, TPB, 0, stream>>>(counts, dinv, n_nodes);
  // scan node counts -> rowptr
  scan_block_kernel<<<scan_blocks, SCAN_B, 0, stream>>>(counts, rowptr, bsum, n_nodes);
  scan_carry_kernel<<<1, 128, 0, stream>>>(bsum, scan_blocks);
  scan_add_kernel<<<node_blocks, TPB, 0, stream>>>(rowptr, bsum, n_nodes, n_edges);
  // scan slot hist -> boff
  scan_block_kernel<<<bscan_blocks, SCAN_B, 0, stream>>>(bh, boff, bsum, n_slot);
  scan_carry_kernel<<<1, 128, 0, stream>>>(bsum, bscan_blocks);
  scan_add_kernel<<<cdiv(n_slot + 1, TPB), TPB, 0, stream>>>(boff, bsum, n_slot, n_edges);
  // sort pass 1: shard-partitioned packed edges
  zero_int_kernel<<<cdiv(n_slot, TPB), TPB, 0, stream>>>(bh, n_slot);  // -> slot cursors
  bucket_scatter_kernel<<<edge_blocks, TPB, 0, stream>>>(e_src, e_dst, boff, bh, ebuf, n_edges);
  // sort pass 2: bucket-private csr fill
  zero_int_kernel<<<node_blocks, TPB, 0, stream>>>(counts, n_nodes);  // -> node cursors
  final_scatter_kernel<<<n_bucket, TPB, 0, stream>>>(ebuf, boff, rowptr, counts, csr_src, n_bucket);

  // ---- pad x / W1 ----
  pad_x8_kernel<<<cdiv(n_nodes * 8, TPB), TPB, 0, stream>>>(x, x8, n_nodes);
  pad_w1_kernel<<<4, TPB, 0, stream>>>(W1, W1p);

  // ---- layer 1: aggx = A_hat x ; h1s(bf16) = relu(aggx @ W1p + b1) * dinv ----
  agg_x_kernel<<<cdiv(n_nodes * 8, TPB), TPB, 0, stream>>>(rowptr, csr_src, dinv, x8, aggx, n_nodes);
  mm_tiled<8, 128, true, false, true><<<mm_blocks, TPB, 0, stream>>>(aggx, W1p, b1, dinv, bufP, n_nodes, 1);
  // bufP = h1s (bf16, prescaled)

  // ---- layer 2: g1(bf16) = dinv * (A_hat-sum of h1s) ; h2 = relu(g1 @ W2 + b2) ----
  gather4_kernel<<<cdiv(n_nodes * 64, TPB), TPB, 0, stream>>>(rowptr, csr_src, dinv,
                                                              (const uint4*)bufP, (uint4*)bufQ, n_nodes);
  mm_tiled<128, 128, false, true, false><<<mm_blocks, TPB, 0, stream>>>(bufQ, W2, b2, nullptr, bufP, n_nodes, 1);
  // bufP = h2 (f32)

  // ---- encoder fc: z = h2 @ Wfc + bfc ----
  mm_tiled<128, 64, false, false, false><<<mm_blocks, TPB, 0, stream>>>(bufP, Wfc, bfc, nullptr, bufR, n_nodes, 0);

  // ---- decoder tables (bf16): atab = z@Wd1_top + bd1 -> bufQ ; btab = z@Wd1_bot -> bufP ----
  unsigned short* atab = (unsigned short*)bufQ;
  unsigned short* btab = (unsigned short*)bufP;
  mm_tiled<64, 128, true, false, false><<<mm_blocks, TPB, 0, stream>>>(bufR, Wd1, bd1, nullptr, atab, n_nodes, 0);
  mm_tiled<64, 128, true, false, false><<<mm_blocks, TPB, 0, stream>>>(bufR, Wd1 + 64 * 128, nullptr, nullptr, btab, n_nodes, 0);

  // ---- per-query decode (MFMA) ----
  decoder_mfma_kernel<<<2048, TPB, 0, stream>>>(q_src, q_dst, atab, btab, Wd2, bd2, Wd3, bd3, out, n_query);
}

// Round 8
// 430.041 us; speedup vs baseline: 1.4853x; 1.4853x over previous
//
#include <hip/hip_runtime.h>
#include <hip/hip_bf16.h>
#include <cstdint>
#include <cstddef>

constexpr int TPB = 256;
constexpr int SCAN_B = 1024;
constexpr int NB   = 128;      // buckets for CSR build
constexpr int BSH  = 10;       // nodes per bucket = 1024
constexpr int NPB  = 1 << BSH;
constexpr int EPB  = 4096;     // edges per block in bucket passes
using bf16x8 = __attribute__((ext_vector_type(8))) short;
using f32x4  = __attribute__((ext_vector_type(4))) float;

static inline int cdiv(int a, int b) { return (a + b - 1) / b; }

__device__ __forceinline__ float bf2f(short u) {
  return __uint_as_float(((unsigned int)(unsigned short)u) << 16);
}
__device__ __forceinline__ short f2bf(float f) {  // RNE
  unsigned int u = __float_as_uint(f);
  return (short)((u + 0x7FFF + ((u >> 16) & 1)) >> 16);
}

// ---------- CSR build: zero global atomics ----------

// per-block LDS bucket hist; write transposed bh[bucket][block]
__global__ __launch_bounds__(256)
void bucket_hist_kernel(const int* __restrict__ dst, int* __restrict__ bh,
                        int e_cnt, int n_blk) {
  __shared__ int h[NB];
  int tid = threadIdx.x;
  if (tid < NB) h[tid] = 0;
  __syncthreads();
  int base = blockIdx.x * EPB;
  for (int i = tid; i < EPB; i += TPB) {
    int e = base + i;
    if (e < e_cnt) atomicAdd(&h[dst[e] >> BSH], 1);
  }
  __syncthreads();
  if (tid < NB) bh[tid * n_blk + blockIdx.x] = h[tid];
}

// multi-block scan, phase 1: per-block exclusive scan + block sums
__global__ __launch_bounds__(SCAN_B)
void scan_block_kernel(const int* __restrict__ counts, int* __restrict__ rowptr,
                       int* __restrict__ bsum, int n) {
  __shared__ int wsum[16];
  const int tid = threadIdx.x;
  const int i = blockIdx.x * SCAN_B + tid;
  const int lane = tid & 63;
  const int w = tid >> 6;
  int v = (i < n) ? counts[i] : 0;
  int s = v;
  #pragma unroll
  for (int off = 1; off < 64; off <<= 1) {
    int t = __shfl_up(s, off, 64);
    if (lane >= off) s += t;
  }
  if (lane == 63) wsum[w] = s;
  __syncthreads();
  if (tid < 16) {
    int ws_ = wsum[tid];
    #pragma unroll
    for (int off = 1; off < 16; off <<= 1) {
      int t = __shfl_up(ws_, off, 64);
      if (tid >= off) ws_ += t;
    }
    wsum[tid] = ws_;
  }
  __syncthreads();
  int woff = (w == 0) ? 0 : wsum[w - 1];
  if (i < n) rowptr[i] = woff + s - v;
  if (tid == SCAN_B - 1) bsum[blockIdx.x] = woff + s;
}

// phase 2: exclusive scan of block sums (nb <= 128)
__global__ void scan_carry_kernel(int* bsum, int nb) {
  __shared__ int w0;
  int tid = threadIdx.x;
  int v = (tid < nb) ? bsum[tid] : 0;
  int s = v;
  #pragma unroll
  for (int off = 1; off < 64; off <<= 1) {
    int t = __shfl_up(s, off, 64);
    if ((tid & 63) >= off) s += t;
  }
  if (tid == 63) w0 = s;
  __syncthreads();
  int incl = s + ((tid >= 64) ? w0 : 0);
  if (tid < nb) bsum[tid] = incl - v;
}

// phase 3: add block offsets (+ write total at [n])
__global__ void scan_add_kernel(int* rowptr, const int* __restrict__ bsum, int n, int total) {
  int i = blockIdx.x * TPB + threadIdx.x;
  if (i < n) rowptr[i] += bsum[i / SCAN_B];
  if (i == 0) rowptr[n] = total;
}

// pass 1 of sort: LDS cursors per bucket; packed plain stores into bucket regions
__global__ __launch_bounds__(256)
void bucket_scatter_kernel(const int* __restrict__ src, const int* __restrict__ dst,
                           const int* __restrict__ eoff, unsigned int* __restrict__ ebuf,
                           int e_cnt, int n_blk) {
  __shared__ int cur[NB];
  int tid = threadIdx.x;
  if (tid < NB) cur[tid] = eoff[tid * n_blk + blockIdx.x];
  __syncthreads();
  int base = blockIdx.x * EPB;
  for (int i = tid; i < EPB; i += TPB) {
    int e = base + i;
    if (e < e_cnt) {
      int d = dst[e];
      int b = d >> BSH;
      int pos = atomicAdd(&cur[b], 1);  // LDS atomic (CU-local)
      ebuf[pos] = ((unsigned int)src[e] << BSH) | (unsigned int)(d & (NPB - 1));
    }
  }
}

// per-bucket node hist from sorted window; counts written wholesale (no atomics)
__global__ __launch_bounds__(256)
void node_hist_kernel(const unsigned int* __restrict__ ebuf, const int* __restrict__ eoff,
                      int* __restrict__ counts, int n_blk, int n_nodes) {
  __shared__ int nh[NPB];
  int b = blockIdx.x;
  for (int i = threadIdx.x; i < NPB; i += TPB) nh[i] = 0;
  __syncthreads();
  int wb = eoff[b * n_blk];
  int we = eoff[(b + 1) * n_blk];   // b=NB-1 hits eoff[NB*n_blk]=e_cnt
  for (int i = wb + threadIdx.x; i < we; i += TPB)
    atomicAdd(&nh[ebuf[i] & (NPB - 1)], 1);  // LDS atomic
  __syncthreads();
  int nbase = b << BSH;
  for (int i = threadIdx.x; i < NPB; i += TPB) {
    int node = nbase + i;
    if (node < n_nodes) counts[node] = nh[i];
  }
}

__global__ void dinv_kernel(const int* __restrict__ counts, float* dinv, int n) {
  int i = blockIdx.x * TPB + threadIdx.x;
  if (i < n) dinv[i] = rsqrtf((float)counts[i] + 1.0f);  // +1 self-loop
}

// pass 2 of sort: per-bucket LDS node cursors seeded from rowptr; csr fill
__global__ __launch_bounds__(256)
void final_scatter_kernel(const unsigned int* __restrict__ ebuf, const int* __restrict__ eoff,
                          const int* __restrict__ rowptr, int* __restrict__ csr_src,
                          int n_blk, int n_nodes) {
  __shared__ int cur[NPB];
  int b = blockIdx.x;
  int nbase = b << BSH;
  for (int i = threadIdx.x; i < NPB; i += TPB) {
    int node = nbase + i;
    cur[i] = (node < n_nodes) ? rowptr[node] : 0;
  }
  __syncthreads();
  int wb = eoff[b * n_blk];
  int we = eoff[(b + 1) * n_blk];
  for (int i = wb + threadIdx.x; i < we; i += TPB) {
    unsigned int p = ebuf[i];
    int pos = atomicAdd(&cur[p & (NPB - 1)], 1);  // LDS atomic
    csr_src[pos] = (int)(p >> BSH);
  }
}

// ---------- dense pipeline (unchanged from R6) ----------

// pad x [n,7] -> x8 [n,8] (8th = 0)
__global__ void pad_x8_kernel(const float* __restrict__ x, float* __restrict__ x8, int n) {
  int i = blockIdx.x * TPB + threadIdx.x;
  if (i >= n * 8) return;
  int node = i >> 3, f = i & 7;
  x8[i] = (f < 7) ? x[node * 7 + f] : 0.0f;
}

// pad W1 [7,128] -> W1p [8,128]
__global__ void pad_w1_kernel(const float* __restrict__ W1, float* __restrict__ W1p) {
  int i = blockIdx.x * TPB + threadIdx.x;
  if (i < 8 * 128) W1p[i] = (i < 7 * 128) ? W1[i] : 0.0f;
}

// aggx = A_hat @ x8 : 8 lanes per node
__global__ __launch_bounds__(256)
void agg_x_kernel(const int* __restrict__ rowptr, const int* __restrict__ csr_src,
                  const float* __restrict__ dinv, const float* __restrict__ x8,
                  float* __restrict__ aggx, int n_nodes) {
  int gid = blockIdx.x * TPB + threadIdx.x;
  int node = gid >> 3;
  int f = gid & 7;
  if (node >= n_nodes) return;
  float dn = dinv[node];
  float acc = x8[(size_t)node * 8 + f] * dn * dn;
  int beg = rowptr[node], end = rowptr[node + 1];
  for (int i = beg; i < end; ++i) {
    int s = csr_src[i];
    acc = fmaf(x8[(size_t)s * 8 + f], dinv[s] * dn, acc);
  }
  aggx[(size_t)node * 8 + f] = acc;
}

// g1 = dinv[n] * ( h1s[n] + sum_{s in N(n)} h1s[s] ); 4 edges/wave, bf16 rows
__global__ __launch_bounds__(256)
void gather4_kernel(const int* __restrict__ rowptr, const int* __restrict__ csr_src,
                    const float* __restrict__ dinv, const uint4* __restrict__ h1s,
                    uint4* __restrict__ g1, int n_nodes) {
  int wid = (blockIdx.x * TPB + threadIdx.x) >> 6;
  if (wid >= n_nodes) return;
  int lane = threadIdx.x & 63;
  int qtr = lane >> 4;
  int l = lane & 15;
  float acc[8];
  #pragma unroll
  for (int j = 0; j < 8; ++j) acc[j] = 0.0f;
  auto addv = [&](uint4 v) {
    unsigned int u[4] = {v.x, v.y, v.z, v.w};
    #pragma unroll
    for (int p = 0; p < 4; ++p) {
      acc[2 * p]     += __uint_as_float(u[p] << 16);
      acc[2 * p + 1] += __uint_as_float(u[p] & 0xffff0000u);
    }
  };
  if (qtr == 0) addv(h1s[(size_t)wid * 16 + l]);  // self term
  int beg = rowptr[wid], end = rowptr[wid + 1];
  int i = beg + qtr;
  for (; i + 4 < end; i += 8) {
    int s0 = csr_src[i];
    int s1 = csr_src[i + 4];
    uint4 v0 = h1s[(size_t)s0 * 16 + l];
    uint4 v1 = h1s[(size_t)s1 * 16 + l];
    addv(v0);
    addv(v1);
  }
  if (i < end) addv(h1s[(size_t)csr_src[i] * 16 + l]);
  #pragma unroll
  for (int j = 0; j < 8; ++j) {
    acc[j] += __shfl_xor(acc[j], 16, 64);
    acc[j] += __shfl_xor(acc[j], 32, 64);
  }
  if (qtr == 0) {
    float dn = dinv[wid];
    unsigned int w[4];
    #pragma unroll
    for (int p = 0; p < 4; ++p) {
      unsigned int lo = (unsigned int)(unsigned short)f2bf(acc[2 * p] * dn);
      unsigned int hi = (unsigned int)(unsigned short)f2bf(acc[2 * p + 1] * dn);
      w[p] = lo | (hi << 16);
    }
    uint4 o; o.x = w[0]; o.y = w[1]; o.z = w[2]; o.w = w[3];
    g1[(size_t)wid * 16 + l] = o;
  }
}

// Register-tiled SGEMM; OB: bf16 out, IB: bf16 in, SC: scale[row] after relu
template<int K, int CO, bool OB, bool IB, bool SC>
__global__ __launch_bounds__(256)
void mm_tiled(const void* __restrict__ inv, const float* __restrict__ W,
              const float* __restrict__ bias, const float* __restrict__ scale,
              void* __restrict__ outv, int n_rows, int do_relu) {
  constexpr int BM = 64;
  constexpr int BK = (K % 32 == 0) ? 32 : K;
  constexpr int SS = BK + 1 + (BK & 1);
  constexpr int TM = 4;
  constexpr int TN = CO / 16;
  __shared__ float s_in[BM][SS];
  __shared__ float s_w[BK][CO];
  const int tid = threadIdx.x;
  const int base = blockIdx.x * BM;
  const int tr = tid >> 4;
  const int tc = tid & 15;

  float acc[TM][TN];
  #pragma unroll
  for (int m = 0; m < TM; ++m)
    #pragma unroll
    for (int n = 0; n < TN; ++n) acc[m][n] = 0.0f;

  for (int kb = 0; kb < K; kb += BK) {
    if constexpr (IB) {
      const unsigned short* inb = (const unsigned short*)inv;
      constexpr int C4 = BK / 4;
      constexpr int F4 = BM * C4;
      #pragma unroll
      for (int t = tid; t < F4; t += TPB) {
        int r = t / C4, c4 = t % C4;
        int row = base + r;
        uint2 v = make_uint2(0u, 0u);
        if (row < n_rows) v = *(const uint2*)(inb + (size_t)row * K + kb + c4 * 4);
        s_in[r][c4 * 4 + 0] = __uint_as_float(v.x << 16);
        s_in[r][c4 * 4 + 1] = __uint_as_float(v.x & 0xffff0000u);
        s_in[r][c4 * 4 + 2] = __uint_as_float(v.y << 16);
        s_in[r][c4 * 4 + 3] = __uint_as_float(v.y & 0xffff0000u);
      }
    } else if constexpr (BK % 4 == 0) {
      const float* in = (const float*)inv;
      constexpr int F4 = BM * (BK / 4);
      #pragma unroll
      for (int t = tid; t < F4; t += TPB) {
        int r = t / (BK / 4), c4 = t % (BK / 4);
        int row = base + r;
        float4 v = make_float4(0.f, 0.f, 0.f, 0.f);
        if (row < n_rows) v = *(const float4*)(in + (size_t)row * K + kb + c4 * 4);
        s_in[r][c4 * 4 + 0] = v.x;
        s_in[r][c4 * 4 + 1] = v.y;
        s_in[r][c4 * 4 + 2] = v.z;
        s_in[r][c4 * 4 + 3] = v.w;
      }
    } else {
      const float* in = (const float*)inv;
      for (int t = tid; t < BM * BK; t += TPB) {
        int r = t / BK, c = t % BK;
        int row = base + r;
        s_in[r][c] = (row < n_rows) ? in[(size_t)row * K + kb + c] : 0.0f;
      }
    }
    {
      constexpr int WF4 = BK * CO / 4;
      #pragma unroll
      for (int t = tid; t < WF4; t += TPB)
        *(float4*)(&s_w[0][0] + t * 4) = *(const float4*)(W + (size_t)kb * CO + t * 4);
    }
    __syncthreads();

    #pragma unroll
    for (int kk = 0; kk < BK; ++kk) {
      float a[TM], b[TN];
      #pragma unroll
      for (int m = 0; m < TM; ++m) a[m] = s_in[tr * TM + m][kk];
      #pragma unroll
      for (int n = 0; n < TN; ++n) b[n] = s_w[kk][tc + 16 * n];
      #pragma unroll
      for (int m = 0; m < TM; ++m)
        #pragma unroll
        for (int n = 0; n < TN; ++n) acc[m][n] = fmaf(a[m], b[n], acc[m][n]);
    }
    __syncthreads();
  }

  #pragma unroll
  for (int m = 0; m < TM; ++m) {
    int row = base + tr * TM + m;
    if (row < n_rows) {
      float sc = 1.0f;
      if constexpr (SC) sc = scale[row];
      #pragma unroll
      for (int n = 0; n < TN; ++n) {
        int j = tc + 16 * n;
        float v = acc[m][n] + (bias ? bias[j] : 0.0f);
        if (do_relu) v = fmaxf(v, 0.0f);
        if constexpr (SC) v *= sc;
        if constexpr (OB)
          ((unsigned short*)outv)[(size_t)row * CO + j] = (unsigned short)f2bf(v);
        else
          ((float*)outv)[(size_t)row * CO + j] = v;
      }
    }
  }
}

// MFMA decoder: 16 queries per wave-tile. (layouts guide-verified)
__global__ __launch_bounds__(256)
void decoder_mfma_kernel(const int* __restrict__ qsrc, const int* __restrict__ qdst,
                         const unsigned short* __restrict__ atab,
                         const unsigned short* __restrict__ btab,
                         const float* __restrict__ Wd2, const float* __restrict__ bd2,
                         const float* __restrict__ Wd3, const float* __restrict__ bd3,
                         float* __restrict__ out, int n_query) {
  const int lane = threadIdx.x & 63;
  const int col = lane & 15;
  const int sub = lane >> 4;

  bf16x8 bfrag[4][4];
  #pragma unroll
  for (int ks = 0; ks < 4; ++ks)
    #pragma unroll
    for (int nt = 0; nt < 4; ++nt) {
      bf16x8 f;
      #pragma unroll
      for (int j = 0; j < 8; ++j) {
        int k = ks * 32 + sub * 8 + j;
        int n = nt * 16 + col;
        f[j] = f2bf(Wd2[k * 64 + n]);
      }
      bfrag[ks][nt] = f;
    }
  float bd2v[4], wd3v[4];
  #pragma unroll
  for (int nt = 0; nt < 4; ++nt) {
    bd2v[nt] = bd2[nt * 16 + col];
    wd3v[nt] = Wd3[nt * 16 + col];
  }
  const float bd3s = bd3[0];

  int wave = (blockIdx.x * TPB + threadIdx.x) >> 6;
  int nwaves = gridDim.x * (TPB / 64);
  int ntiles = (n_query + 15) >> 4;
  for (int t = wave; t < ntiles; t += nwaves) {
    int qb = t << 4;
    int q = qb + col;
    if (q >= n_query) q = n_query - 1;
    int si = qsrc[q], di = qdst[q];
    const bf16x8* ar = (const bf16x8*)(atab + (size_t)si * 128);
    const bf16x8* br = (const bf16x8*)(btab + (size_t)di * 128);
    bf16x8 afrag[4];
    #pragma unroll
    for (int ks = 0; ks < 4; ++ks) {
      bf16x8 av = ar[ks * 4 + sub];
      bf16x8 bv = br[ks * 4 + sub];
      bf16x8 d;
      #pragma unroll
      for (int j = 0; j < 8; ++j)
        d[j] = f2bf(fmaxf(bf2f(av[j]) + bf2f(bv[j]), 0.0f));  // d1 = relu(a+b)
      afrag[ks] = d;
    }
    f32x4 acc[4];
    #pragma unroll
    for (int nt = 0; nt < 4; ++nt) acc[nt] = {0.f, 0.f, 0.f, 0.f};
    #pragma unroll
    for (int ks = 0; ks < 4; ++ks)
      #pragma unroll
      for (int nt = 0; nt < 4; ++nt)
        acc[nt] = __builtin_amdgcn_mfma_f32_16x16x32_bf16(afrag[ks], bfrag[ks][nt], acc[nt], 0, 0, 0);
    float part[4] = {0.f, 0.f, 0.f, 0.f};
    #pragma unroll
    for (int nt = 0; nt < 4; ++nt)
      #pragma unroll
      for (int r = 0; r < 4; ++r) {
        float v = fmaxf(acc[nt][r] + bd2v[nt], 0.0f);
        part[r] = fmaf(v, wd3v[nt], part[r]);
      }
    #pragma unroll
    for (int off = 1; off < 16; off <<= 1)
      #pragma unroll
      for (int r = 0; r < 4; ++r) part[r] += __shfl_xor(part[r], off, 64);
    if (col == 0) {
      int row0 = qb + sub * 4;
      #pragma unroll
      for (int r = 0; r < 4; ++r) {
        int qq = row0 + r;
        if (qq < n_query) out[qq] = 1.0f / (1.0f + __expf(-(part[r] + bd3s)));
      }
    }
  }
}

extern "C" void kernel_launch(void* const* d_in, const int* in_sizes, int n_in,
                              void* d_out, int out_size, void* d_ws, size_t ws_size,
                              hipStream_t stream) {
  const float* x    = (const float*)d_in[0];
  const int*   ei   = (const int*)d_in[1];
  const int*   qe   = (const int*)d_in[2];
  const float* W1   = (const float*)d_in[3];
  const float* b1   = (const float*)d_in[4];
  const float* W2   = (const float*)d_in[5];
  const float* b2   = (const float*)d_in[6];
  const float* Wfc  = (const float*)d_in[7];
  const float* bfc  = (const float*)d_in[8];
  const float* Wd1  = (const float*)d_in[9];
  const float* bd1  = (const float*)d_in[10];
  const float* Wd2  = (const float*)d_in[11];
  const float* bd2  = (const float*)d_in[12];
  const float* Wd3  = (const float*)d_in[13];
  const float* bd3  = (const float*)d_in[14];
  float* out = (float*)d_out;

  const int n_nodes = in_sizes[0] / 7;
  const int n_edges = in_sizes[1] / 2;
  const int n_query = in_sizes[2] / 2;
  const int* e_src = ei;
  const int* e_dst = ei + n_edges;
  const int* q_src = qe;
  const int* q_dst = qe + n_query;

  const int n_blk1 = cdiv(n_edges, EPB);          // blocks in bucket passes
  const int bh_len = NB * n_blk1;                 // transposed hist length
  const int n_bucket = cdiv(n_nodes, NPB);        // active buckets

  // ---- workspace layout ----
  char* wp = (char*)d_ws;
  auto take = [&](size_t bytes) { char* p = wp; wp += (bytes + 255) & ~size_t(255); return p; };
  float* dinv    = (float*)take((size_t)n_nodes * 4);
  int*   counts  = (int*)  take((size_t)n_nodes * 4);
  int*   rowptr  = (int*)  take((size_t)(n_nodes + 1) * 4);
  int*   bsum    = (int*)  take(512 * 4);
  int*   bh      = (int*)  take((size_t)(bh_len + 1) * 4);
  int*   eoff    = (int*)  take((size_t)(bh_len + 1) * 4);
  unsigned int* ebuf = (unsigned int*)take((size_t)n_edges * 4);
  int*   csr_src = (int*)  take((size_t)n_edges * 4);
  float* x8      = (float*)take((size_t)n_nodes * 8 * 4);
  float* aggx    = (float*)take((size_t)n_nodes * 8 * 4);
  float* W1p     = (float*)take(8 * 128 * 4);
  float* bufP    = (float*)take((size_t)n_nodes * 128 * 4);
  float* bufQ    = (float*)take((size_t)n_nodes * 128 * 4);
  float* bufR    = (float*)take((size_t)n_nodes * 64 * 4);

  const int mm_blocks = cdiv(n_nodes, 64);
  const int node_blocks = cdiv(n_nodes, TPB);
  const int scan_blocks = cdiv(n_nodes, SCAN_B);
  const int escan_blocks = cdiv(bh_len, SCAN_B);

  // ---- CSR build (no global atomics) ----
  bucket_hist_kernel<<<n_blk1, TPB, 0, stream>>>(e_dst, bh, n_edges, n_blk1);
  scan_block_kernel<<<escan_blocks, SCAN_B, 0, stream>>>(bh, eoff, bsum, bh_len);
  scan_carry_kernel<<<1, 128, 0, stream>>>(bsum, escan_blocks);
  scan_add_kernel<<<cdiv(bh_len, TPB), TPB, 0, stream>>>(eoff, bsum, bh_len, n_edges);
  bucket_scatter_kernel<<<n_blk1, TPB, 0, stream>>>(e_src, e_dst, eoff, ebuf, n_edges, n_blk1);
  node_hist_kernel<<<n_bucket, TPB, 0, stream>>>(ebuf, eoff, counts, n_blk1, n_nodes);
  dinv_kernel<<<node_blocks, TPB, 0, stream>>>(counts, dinv, n_nodes);
  scan_block_kernel<<<scan_blocks, SCAN_B, 0, stream>>>(counts, rowptr, bsum, n_nodes);
  scan_carry_kernel<<<1, 128, 0, stream>>>(bsum, scan_blocks);
  scan_add_kernel<<<node_blocks, TPB, 0, stream>>>(rowptr, bsum, n_nodes, n_edges);
  final_scatter_kernel<<<n_bucket, TPB, 0, stream>>>(ebuf, eoff, rowptr, csr_src, n_blk1, n_nodes);

  // ---- pad x / W1 ----
  pad_x8_kernel<<<cdiv(n_nodes * 8, TPB), TPB, 0, stream>>>(x, x8, n_nodes);
  pad_w1_kernel<<<4, TPB, 0, stream>>>(W1, W1p);

  // ---- layer 1: aggx = A_hat x ; h1s(bf16) = relu(aggx @ W1p + b1) * dinv ----
  agg_x_kernel<<<cdiv(n_nodes * 8, TPB), TPB, 0, stream>>>(rowptr, csr_src, dinv, x8, aggx, n_nodes);
  mm_tiled<8, 128, true, false, true><<<mm_blocks, TPB, 0, stream>>>(aggx, W1p, b1, dinv, bufP, n_nodes, 1);
  // bufP = h1s (bf16, prescaled)

  // ---- layer 2: g1(bf16) = dinv * (A_hat-sum of h1s) ; h2 = relu(g1 @ W2 + b2) ----
  gather4_kernel<<<cdiv(n_nodes * 64, TPB), TPB, 0, stream>>>(rowptr, csr_src, dinv,
                                                              (const uint4*)bufP, (uint4*)bufQ, n_nodes);
  mm_tiled<128, 128, false, true, false><<<mm_blocks, TPB, 0, stream>>>(bufQ, W2, b2, nullptr, bufP, n_nodes, 1);
  // bufP = h2 (f32)

  // ---- encoder fc: z = h2 @ Wfc + bfc ----
  mm_tiled<128, 64, false, false, false><<<mm_blocks, TPB, 0, stream>>>(bufP, Wfc, bfc, nullptr, bufR, n_nodes, 0);

  // ---- decoder tables (bf16): atab = z@Wd1_top + bd1 ; btab = z@Wd1_bot ----
  unsigned short* atab = (unsigned short*)bufQ;
  unsigned short* btab = (unsigned short*)bufP;
  mm_tiled<64, 128, true, false, false><<<mm_blocks, TPB, 0, stream>>>(bufR, Wd1, bd1, nullptr, atab, n_nodes, 0);
  mm_tiled<64, 128, true, false, false><<<mm_blocks, TPB, 0, stream>>>(bufR, Wd1 + 64 * 128, nullptr, nullptr, btab, n_nodes, 0);

  // ---- per-query decode (MFMA) ----
  decoder_mfma_kernel<<<2048, TPB, 0, stream>>>(q_src, q_dst, atab, btab, Wd2, bd2, Wd3, bd3, out, n_query);
}

// Round 9
// 319.619 us; speedup vs baseline: 1.9984x; 1.3455x over previous
//
#include <hip/hip_runtime.h>
#include <hip/hip_bf16.h>
#include <cstdint>
#include <cstddef>

constexpr int TPB = 256;
constexpr int SCAN_B = 1024;
constexpr int NB   = 128;      // buckets for CSR build
constexpr int BSH  = 10;       // nodes per bucket = 1024
constexpr int NPB  = 1 << BSH;
constexpr int EPB  = 4096;     // edges per block in bucket passes
using bf16x8 = __attribute__((ext_vector_type(8))) short;
using f32x4  = __attribute__((ext_vector_type(4))) float;

static inline int cdiv(int a, int b) { return (a + b - 1) / b; }

__device__ __forceinline__ float bf2f(short u) {
  return __uint_as_float(((unsigned int)(unsigned short)u) << 16);
}
__device__ __forceinline__ short f2bf(float f) {  // RNE
  unsigned int u = __float_as_uint(f);
  return (short)((u + 0x7FFF + ((u >> 16) & 1)) >> 16);
}

// ---------- CSR build: zero global atomics ----------

__global__ __launch_bounds__(256)
void bucket_hist_kernel(const int* __restrict__ dst, int* __restrict__ bh,
                        int e_cnt, int n_blk) {
  __shared__ int h[NB];
  int tid = threadIdx.x;
  if (tid < NB) h[tid] = 0;
  __syncthreads();
  int base = blockIdx.x * EPB;
  for (int i = tid; i < EPB; i += TPB) {
    int e = base + i;
    if (e < e_cnt) atomicAdd(&h[dst[e] >> BSH], 1);
  }
  __syncthreads();
  if (tid < NB) bh[tid * n_blk + blockIdx.x] = h[tid];
}

__global__ __launch_bounds__(SCAN_B)
void scan_block_kernel(const int* __restrict__ counts, int* __restrict__ rowptr,
                       int* __restrict__ bsum, int n) {
  __shared__ int wsum[16];
  const int tid = threadIdx.x;
  const int i = blockIdx.x * SCAN_B + tid;
  const int lane = tid & 63;
  const int w = tid >> 6;
  int v = (i < n) ? counts[i] : 0;
  int s = v;
  #pragma unroll
  for (int off = 1; off < 64; off <<= 1) {
    int t = __shfl_up(s, off, 64);
    if (lane >= off) s += t;
  }
  if (lane == 63) wsum[w] = s;
  __syncthreads();
  if (tid < 16) {
    int ws_ = wsum[tid];
    #pragma unroll
    for (int off = 1; off < 16; off <<= 1) {
      int t = __shfl_up(ws_, off, 64);
      if (tid >= off) ws_ += t;
    }
    wsum[tid] = ws_;
  }
  __syncthreads();
  int woff = (w == 0) ? 0 : wsum[w - 1];
  if (i < n) rowptr[i] = woff + s - v;
  if (tid == SCAN_B - 1) bsum[blockIdx.x] = woff + s;
}

__global__ void scan_carry_kernel(int* bsum, int nb) {
  __shared__ int w0;
  int tid = threadIdx.x;
  int v = (tid < nb) ? bsum[tid] : 0;
  int s = v;
  #pragma unroll
  for (int off = 1; off < 64; off <<= 1) {
    int t = __shfl_up(s, off, 64);
    if ((tid & 63) >= off) s += t;
  }
  if (tid == 63) w0 = s;
  __syncthreads();
  int incl = s + ((tid >= 64) ? w0 : 0);
  if (tid < nb) bsum[tid] = incl - v;
}

__global__ void scan_add_kernel(int* rowptr, const int* __restrict__ bsum, int n, int total) {
  int i = blockIdx.x * TPB + threadIdx.x;
  if (i < n) rowptr[i] += bsum[i / SCAN_B];
  if (i == 0) rowptr[n] = total;
}

__global__ __launch_bounds__(256)
void bucket_scatter_kernel(const int* __restrict__ src, const int* __restrict__ dst,
                           const int* __restrict__ eoff, unsigned int* __restrict__ ebuf,
                           int e_cnt, int n_blk) {
  __shared__ int cur[NB];
  int tid = threadIdx.x;
  if (tid < NB) cur[tid] = eoff[tid * n_blk + blockIdx.x];
  __syncthreads();
  int base = blockIdx.x * EPB;
  for (int i = tid; i < EPB; i += TPB) {
    int e = base + i;
    if (e < e_cnt) {
      int d = dst[e];
      int b = d >> BSH;
      int pos = atomicAdd(&cur[b], 1);  // LDS atomic
      ebuf[pos] = ((unsigned int)src[e] << BSH) | (unsigned int)(d & (NPB - 1));
    }
  }
}

__global__ __launch_bounds__(256)
void node_hist_kernel(const unsigned int* __restrict__ ebuf, const int* __restrict__ eoff,
                      int* __restrict__ counts, int n_blk, int n_nodes) {
  __shared__ int nh[NPB];
  int b = blockIdx.x;
  for (int i = threadIdx.x; i < NPB; i += TPB) nh[i] = 0;
  __syncthreads();
  int wb = eoff[b * n_blk];
  int we = eoff[(b + 1) * n_blk];
  for (int i = wb + threadIdx.x; i < we; i += TPB)
    atomicAdd(&nh[ebuf[i] & (NPB - 1)], 1);  // LDS atomic
  __syncthreads();
  int nbase = b << BSH;
  for (int i = threadIdx.x; i < NPB; i += TPB) {
    int node = nbase + i;
    if (node < n_nodes) counts[node] = nh[i];
  }
}

__global__ void dinv_kernel(const int* __restrict__ counts, float* dinv, int n) {
  int i = blockIdx.x * TPB + threadIdx.x;
  if (i < n) dinv[i] = rsqrtf((float)counts[i] + 1.0f);  // +1 self-loop
}

__global__ __launch_bounds__(256)
void final_scatter_kernel(const unsigned int* __restrict__ ebuf, const int* __restrict__ eoff,
                          const int* __restrict__ rowptr, int* __restrict__ csr_src,
                          int n_blk, int n_nodes) {
  __shared__ int cur[NPB];
  int b = blockIdx.x;
  int nbase = b << BSH;
  for (int i = threadIdx.x; i < NPB; i += TPB) {
    int node = nbase + i;
    cur[i] = (node < n_nodes) ? rowptr[node] : 0;
  }
  __syncthreads();
  int wb = eoff[b * n_blk];
  int we = eoff[(b + 1) * n_blk];
  for (int i = wb + threadIdx.x; i < we; i += TPB) {
    unsigned int p = ebuf[i];
    int pos = atomicAdd(&cur[p & (NPB - 1)], 1);  // LDS atomic
    csr_src[pos] = (int)(p >> BSH);
  }
}

// ---------- dense pipeline ----------

__global__ void pad_x8_kernel(const float* __restrict__ x, float* __restrict__ x8, int n) {
  int i = blockIdx.x * TPB + threadIdx.x;
  if (i >= n * 8) return;
  int node = i >> 3, f = i & 7;
  x8[i] = (f < 7) ? x[node * 7 + f] : 0.0f;
}

__global__ void pad_w1_kernel(const float* __restrict__ W1, float* __restrict__ W1p) {
  int i = blockIdx.x * TPB + threadIdx.x;
  if (i < 8 * 128) W1p[i] = (i < 7 * 128) ? W1[i] : 0.0f;
}

// transpose+convert W[K][N] (f32) -> WT[N][K] (bf16)
__global__ void wconv_kernel(const float* __restrict__ in, unsigned short* __restrict__ out,
                             int K, int N) {
  int i = blockIdx.x * TPB + threadIdx.x;
  if (i >= K * N) return;
  int k = i / N, n = i - k * N;
  out[(size_t)n * K + k] = (unsigned short)f2bf(in[i]);
}

// aggx = A_hat @ x8 : 8 lanes per node
__global__ __launch_bounds__(256)
void agg_x_kernel(const int* __restrict__ rowptr, const int* __restrict__ csr_src,
                  const float* __restrict__ dinv, const float* __restrict__ x8,
                  float* __restrict__ aggx, int n_nodes) {
  int gid = blockIdx.x * TPB + threadIdx.x;
  int node = gid >> 3;
  int f = gid & 7;
  if (node >= n_nodes) return;
  float dn = dinv[node];
  float acc = x8[(size_t)node * 8 + f] * dn * dn;
  int beg = rowptr[node], end = rowptr[node + 1];
  for (int i = beg; i < end; ++i) {
    int s = csr_src[i];
    acc = fmaf(x8[(size_t)s * 8 + f], dinv[s] * dn, acc);
  }
  aggx[(size_t)node * 8 + f] = acc;
}

// g1 = dinv[n] * ( h1s[n] + sum_{s in N(n)} h1s[s] ); 4 edges/wave, bf16 rows
__global__ __launch_bounds__(256)
void gather4_kernel(const int* __restrict__ rowptr, const int* __restrict__ csr_src,
                    const float* __restrict__ dinv, const uint4* __restrict__ h1s,
                    uint4* __restrict__ g1, int n_nodes) {
  int wid = (blockIdx.x * TPB + threadIdx.x) >> 6;
  if (wid >= n_nodes) return;
  int lane = threadIdx.x & 63;
  int qtr = lane >> 4;
  int l = lane & 15;
  float acc[8];
  #pragma unroll
  for (int j = 0; j < 8; ++j) acc[j] = 0.0f;
  auto addv = [&](uint4 v) {
    unsigned int u[4] = {v.x, v.y, v.z, v.w};
    #pragma unroll
    for (int p = 0; p < 4; ++p) {
      acc[2 * p]     += __uint_as_float(u[p] << 16);
      acc[2 * p + 1] += __uint_as_float(u[p] & 0xffff0000u);
    }
  };
  if (qtr == 0) addv(h1s[(size_t)wid * 16 + l]);  // self term
  int beg = rowptr[wid], end = rowptr[wid + 1];
  int i = beg + qtr;
  for (; i + 4 < end; i += 8) {
    int s0 = csr_src[i];
    int s1 = csr_src[i + 4];
    uint4 v0 = h1s[(size_t)s0 * 16 + l];
    uint4 v1 = h1s[(size_t)s1 * 16 + l];
    addv(v0);
    addv(v1);
  }
  if (i < end) addv(h1s[(size_t)csr_src[i] * 16 + l]);
  #pragma unroll
  for (int j = 0; j < 8; ++j) {
    acc[j] += __shfl_xor(acc[j], 16, 64);
    acc[j] += __shfl_xor(acc[j], 32, 64);
  }
  if (qtr == 0) {
    float dn = dinv[wid];
    unsigned int w[4];
    #pragma unroll
    for (int p = 0; p < 4; ++p) {
      unsigned int lo = (unsigned int)(unsigned short)f2bf(acc[2 * p] * dn);
      unsigned int hi = (unsigned int)(unsigned short)f2bf(acc[2 * p + 1] * dn);
      w[p] = lo | (hi << 16);
    }
    uint4 o; o.x = w[0]; o.y = w[1]; o.z = w[2]; o.w = w[3];
    g1[(size_t)wid * 16 + l] = o;
  }
}

// Register-tiled SGEMM (layer-1 only: K=8); OB bf16 out, SC scale[row] after relu
template<int K, int CO, bool OB, bool SC>
__global__ __launch_bounds__(256)
void mm_tiled(const float* __restrict__ in, const float* __restrict__ W,
              const float* __restrict__ bias, const float* __restrict__ scale,
              void* __restrict__ outv, int n_rows, int do_relu) {
  constexpr int BM = 64;
  constexpr int BK = (K % 32 == 0) ? 32 : K;
  constexpr int SS = BK + 1 + (BK & 1);
  constexpr int TM = 4;
  constexpr int TN = CO / 16;
  __shared__ float s_in[BM][SS];
  __shared__ float s_w[BK][CO];
  const int tid = threadIdx.x;
  const int base = blockIdx.x * BM;
  const int tr = tid >> 4;
  const int tc = tid & 15;

  float acc[TM][TN];
  #pragma unroll
  for (int m = 0; m < TM; ++m)
    #pragma unroll
    for (int n = 0; n < TN; ++n) acc[m][n] = 0.0f;

  for (int kb = 0; kb < K; kb += BK) {
    if constexpr (BK % 4 == 0) {
      constexpr int F4 = BM * (BK / 4);
      #pragma unroll
      for (int t = tid; t < F4; t += TPB) {
        int r = t / (BK / 4), c4 = t % (BK / 4);
        int row = base + r;
        float4 v = make_float4(0.f, 0.f, 0.f, 0.f);
        if (row < n_rows) v = *(const float4*)(in + (size_t)row * K + kb + c4 * 4);
        s_in[r][c4 * 4 + 0] = v.x;
        s_in[r][c4 * 4 + 1] = v.y;
        s_in[r][c4 * 4 + 2] = v.z;
        s_in[r][c4 * 4 + 3] = v.w;
      }
    } else {
      for (int t = tid; t < BM * BK; t += TPB) {
        int r = t / BK, c = t % BK;
        int row = base + r;
        s_in[r][c] = (row < n_rows) ? in[(size_t)row * K + kb + c] : 0.0f;
      }
    }
    {
      constexpr int WF4 = BK * CO / 4;
      #pragma unroll
      for (int t = tid; t < WF4; t += TPB)
        *(float4*)(&s_w[0][0] + t * 4) = *(const float4*)(W + (size_t)kb * CO + t * 4);
    }
    __syncthreads();

    #pragma unroll
    for (int kk = 0; kk < BK; ++kk) {
      float a[TM], b[TN];
      #pragma unroll
      for (int m = 0; m < TM; ++m) a[m] = s_in[tr * TM + m][kk];
      #pragma unroll
      for (int n = 0; n < TN; ++n) b[n] = s_w[kk][tc + 16 * n];
      #pragma unroll
      for (int m = 0; m < TM; ++m)
        #pragma unroll
        for (int n = 0; n < TN; ++n) acc[m][n] = fmaf(a[m], b[n], acc[m][n]);
    }
    __syncthreads();
  }

  #pragma unroll
  for (int m = 0; m < TM; ++m) {
    int row = base + tr * TM + m;
    if (row < n_rows) {
      float sc = 1.0f;
      if constexpr (SC) sc = scale[row];
      #pragma unroll
      for (int n = 0; n < TN; ++n) {
        int j = tc + 16 * n;
        float v = acc[m][n] + (bias ? bias[j] : 0.0f);
        if (do_relu) v = fmaxf(v, 0.0f);
        if constexpr (SC) v *= sc;
        if constexpr (OB)
          ((unsigned short*)outv)[(size_t)row * CO + j] = (unsigned short)f2bf(v);
        else
          ((float*)outv)[(size_t)row * CO + j] = v;
      }
    }
  }
}

// MFMA GEMM: out(bf16)[n_rows,N] = A(bf16)[n_rows,K] @ WT(bf16)[N,K]^T (+bias)(+relu)
// Fragment layouts identical to decoder (validated): A row=lane&15, k=sub*8+j;
// B col=lane&15, k=sub*8+j; C/D col=lane&15, row=sub*4+r.
template<int K, int N>
__global__ __launch_bounds__(256)
void mm_mfma(const unsigned short* __restrict__ A, const unsigned short* __restrict__ WT,
             const float* __restrict__ bias, unsigned short* __restrict__ out,
             int n_rows, int do_relu) {
  constexpr int KS = K / 32;
  constexpr int NT = N / 16;
  const int lane = threadIdx.x & 63;
  const int col = lane & 15;
  const int sub = lane >> 4;
  const int wid = threadIdx.x >> 6;

  bf16x8 bfrag[KS][NT];
  #pragma unroll
  for (int ks = 0; ks < KS; ++ks)
    #pragma unroll
    for (int nt = 0; nt < NT; ++nt)
      bfrag[ks][nt] = *(const bf16x8*)(WT + (size_t)(nt * 16 + col) * K + ks * 32 + sub * 8);
  float bv[NT];
  #pragma unroll
  for (int nt = 0; nt < NT; ++nt) bv[nt] = bias ? bias[nt * 16 + col] : 0.0f;

  int ntiles = (n_rows + 15) >> 4;
  int stride = gridDim.x * 4;
  for (int tile = blockIdx.x * 4 + wid; tile < ntiles; tile += stride) {
    int row_a = tile * 16 + col;
    if (row_a >= n_rows) row_a = n_rows - 1;
    bf16x8 afrag[KS];
    #pragma unroll
    for (int ks = 0; ks < KS; ++ks)
      afrag[ks] = *(const bf16x8*)(A + (size_t)row_a * K + ks * 32 + sub * 8);
    f32x4 acc[NT];
    #pragma unroll
    for (int nt = 0; nt < NT; ++nt) acc[nt] = {0.f, 0.f, 0.f, 0.f};
    #pragma unroll
    for (int ks = 0; ks < KS; ++ks)
      #pragma unroll
      for (int nt = 0; nt < NT; ++nt)
        acc[nt] = __builtin_amdgcn_mfma_f32_16x16x32_bf16(afrag[ks], bfrag[ks][nt], acc[nt], 0, 0, 0);
    #pragma unroll
    for (int r = 0; r < 4; ++r) {
      int ro = tile * 16 + sub * 4 + r;
      if (ro < n_rows) {
        #pragma unroll
        for (int nt = 0; nt < NT; ++nt) {
          float v = acc[nt][r] + bv[nt];
          if (do_relu) v = fmaxf(v, 0.0f);
          out[(size_t)ro * N + nt * 16 + col] = (unsigned short)f2bf(v);
        }
      }
    }
  }
}

// MFMA decoder: 16 queries per wave-tile. (layouts validated)
__global__ __launch_bounds__(256)
void decoder_mfma_kernel(const int* __restrict__ qsrc, const int* __restrict__ qdst,
                         const unsigned short* __restrict__ atab,
                         const unsigned short* __restrict__ btab,
                         const float* __restrict__ Wd2, const float* __restrict__ bd2,
                         const float* __restrict__ Wd3, const float* __restrict__ bd3,
                         float* __restrict__ out, int n_query) {
  const int lane = threadIdx.x & 63;
  const int col = lane & 15;
  const int sub = lane >> 4;

  bf16x8 bfrag[4][4];
  #pragma unroll
  for (int ks = 0; ks < 4; ++ks)
    #pragma unroll
    for (int nt = 0; nt < 4; ++nt) {
      bf16x8 f;
      #pragma unroll
      for (int j = 0; j < 8; ++j) {
        int k = ks * 32 + sub * 8 + j;
        int n = nt * 16 + col;
        f[j] = f2bf(Wd2[k * 64 + n]);
      }
      bfrag[ks][nt] = f;
    }
  float bd2v[4], wd3v[4];
  #pragma unroll
  for (int nt = 0; nt < 4; ++nt) {
    bd2v[nt] = bd2[nt * 16 + col];
    wd3v[nt] = Wd3[nt * 16 + col];
  }
  const float bd3s = bd3[0];

  int wave = (blockIdx.x * TPB + threadIdx.x) >> 6;
  int nwaves = gridDim.x * (TPB / 64);
  int ntiles = (n_query + 15) >> 4;
  for (int t = wave; t < ntiles; t += nwaves) {
    int qb = t << 4;
    int q = qb + col;
    if (q >= n_query) q = n_query - 1;
    int si = qsrc[q], di = qdst[q];
    const bf16x8* ar = (const bf16x8*)(atab + (size_t)si * 128);
    const bf16x8* br = (const bf16x8*)(btab + (size_t)di * 128);
    bf16x8 afrag[4];
    #pragma unroll
    for (int ks = 0; ks < 4; ++ks) {
      bf16x8 av = ar[ks * 4 + sub];
      bf16x8 bv = br[ks * 4 + sub];
      bf16x8 d;
      #pragma unroll
      for (int j = 0; j < 8; ++j)
        d[j] = f2bf(fmaxf(bf2f(av[j]) + bf2f(bv[j]), 0.0f));  // d1 = relu(a+b)
      afrag[ks] = d;
    }
    f32x4 acc[4];
    #pragma unroll
    for (int nt = 0; nt < 4; ++nt) acc[nt] = {0.f, 0.f, 0.f, 0.f};
    #pragma unroll
    for (int ks = 0; ks < 4; ++ks)
      #pragma unroll
      for (int nt = 0; nt < 4; ++nt)
        acc[nt] = __builtin_amdgcn_mfma_f32_16x16x32_bf16(afrag[ks], bfrag[ks][nt], acc[nt], 0, 0, 0);
    float part[4] = {0.f, 0.f, 0.f, 0.f};
    #pragma unroll
    for (int nt = 0; nt < 4; ++nt)
      #pragma unroll
      for (int r = 0; r < 4; ++r) {
        float v = fmaxf(acc[nt][r] + bd2v[nt], 0.0f);
        part[r] = fmaf(v, wd3v[nt], part[r]);
      }
    #pragma unroll
    for (int off = 1; off < 16; off <<= 1)
      #pragma unroll
      for (int r = 0; r < 4; ++r) part[r] += __shfl_xor(part[r], off, 64);
    if (col == 0) {
      int row0 = qb + sub * 4;
      #pragma unroll
      for (int r = 0; r < 4; ++r) {
        int qq = row0 + r;
        if (qq < n_query) out[qq] = 1.0f / (1.0f + __expf(-(part[r] + bd3s)));
      }
    }
  }
}

extern "C" void kernel_launch(void* const* d_in, const int* in_sizes, int n_in,
                              void* d_out, int out_size, void* d_ws, size_t ws_size,
                              hipStream_t stream) {
  const float* x    = (const float*)d_in[0];
  const int*   ei   = (const int*)d_in[1];
  const int*   qe   = (const int*)d_in[2];
  const float* W1   = (const float*)d_in[3];
  const float* b1   = (const float*)d_in[4];
  const float* W2   = (const float*)d_in[5];
  const float* b2   = (const float*)d_in[6];
  const float* Wfc  = (const float*)d_in[7];
  const float* bfc  = (const float*)d_in[8];
  const float* Wd1  = (const float*)d_in[9];
  const float* bd1  = (const float*)d_in[10];
  const float* Wd2  = (const float*)d_in[11];
  const float* bd2  = (const float*)d_in[12];
  const float* Wd3  = (const float*)d_in[13];
  const float* bd3  = (const float*)d_in[14];
  float* out = (float*)d_out;

  const int n_nodes = in_sizes[0] / 7;
  const int n_edges = in_sizes[1] / 2;
  const int n_query = in_sizes[2] / 2;
  const int* e_src = ei;
  const int* e_dst = ei + n_edges;
  const int* q_src = qe;
  const int* q_dst = qe + n_query;

  const int n_blk1 = cdiv(n_edges, EPB);
  const int bh_len = NB * n_blk1;
  const int n_bucket = cdiv(n_nodes, NPB);

  // ---- workspace layout ----
  char* wp = (char*)d_ws;
  auto take = [&](size_t bytes) { char* p = wp; wp += (bytes + 255) & ~size_t(255); return p; };
  float* dinv    = (float*)take((size_t)n_nodes * 4);
  int*   counts  = (int*)  take((size_t)n_nodes * 4);
  int*   rowptr  = (int*)  take((size_t)(n_nodes + 1) * 4);
  int*   bsum    = (int*)  take(512 * 4);
  int*   bh      = (int*)  take((size_t)(bh_len + 1) * 4);
  int*   eoff    = (int*)  take((size_t)(bh_len + 1) * 4);
  unsigned int* ebuf = (unsigned int*)take((size_t)n_edges * 4);
  int*   csr_src = (int*)  take((size_t)n_edges * 4);
  float* x8      = (float*)take((size_t)n_nodes * 8 * 4);
  float* aggx    = (float*)take((size_t)n_nodes * 8 * 4);
  float* W1p     = (float*)take(8 * 128 * 4);
  unsigned short* W2T   = (unsigned short*)take(128 * 128 * 2);
  unsigned short* WfcT  = (unsigned short*)take(64 * 128 * 2);
  unsigned short* Wd1aT = (unsigned short*)take(128 * 64 * 2);
  unsigned short* Wd1bT = (unsigned short*)take(128 * 64 * 2);
  float* bufP    = (float*)take((size_t)n_nodes * 128 * 4);
  float* bufQ    = (float*)take((size_t)n_nodes * 128 * 4);
  float* bufR    = (float*)take((size_t)n_nodes * 64 * 4);

  const int mm_blocks = cdiv(n_nodes, 64);
  const int node_blocks = cdiv(n_nodes, TPB);
  const int scan_blocks = cdiv(n_nodes, SCAN_B);
  const int escan_blocks = cdiv(bh_len, SCAN_B);
  const int mfma_blocks = min(1024, cdiv(cdiv(n_nodes, 16), 4));

  // ---- CSR build (no global atomics) ----
  bucket_hist_kernel<<<n_blk1, TPB, 0, stream>>>(e_dst, bh, n_edges, n_blk1);
  scan_block_kernel<<<escan_blocks, SCAN_B, 0, stream>>>(bh, eoff, bsum, bh_len);
  scan_carry_kernel<<<1, 128, 0, stream>>>(bsum, escan_blocks);
  scan_add_kernel<<<cdiv(bh_len, TPB), TPB, 0, stream>>>(eoff, bsum, bh_len, n_edges);
  bucket_scatter_kernel<<<n_blk1, TPB, 0, stream>>>(e_src, e_dst, eoff, ebuf, n_edges, n_blk1);
  node_hist_kernel<<<n_bucket, TPB, 0, stream>>>(ebuf, eoff, counts, n_blk1, n_nodes);
  dinv_kernel<<<node_blocks, TPB, 0, stream>>>(counts, dinv, n_nodes);
  scan_block_kernel<<<scan_blocks, SCAN_B, 0, stream>>>(counts, rowptr, bsum, n_nodes);
  scan_carry_kernel<<<1, 128, 0, stream>>>(bsum, scan_blocks);
  scan_add_kernel<<<node_blocks, TPB, 0, stream>>>(rowptr, bsum, n_nodes, n_edges);
  final_scatter_kernel<<<n_bucket, TPB, 0, stream>>>(ebuf, eoff, rowptr, csr_src, n_blk1, n_nodes);

  // ---- pads + weight transposes ----
  pad_x8_kernel<<<cdiv(n_nodes * 8, TPB), TPB, 0, stream>>>(x, x8, n_nodes);
  pad_w1_kernel<<<4, TPB, 0, stream>>>(W1, W1p);
  wconv_kernel<<<cdiv(128 * 128, TPB), TPB, 0, stream>>>(W2, W2T, 128, 128);
  wconv_kernel<<<cdiv(128 * 64, TPB), TPB, 0, stream>>>(Wfc, WfcT, 128, 64);
  wconv_kernel<<<cdiv(64 * 128, TPB), TPB, 0, stream>>>(Wd1, Wd1aT, 64, 128);
  wconv_kernel<<<cdiv(64 * 128, TPB), TPB, 0, stream>>>(Wd1 + 64 * 128, Wd1bT, 64, 128);

  // ---- layer 1: aggx = A_hat x ; h1s(bf16) = relu(aggx @ W1p + b1) * dinv ----
  agg_x_kernel<<<cdiv(n_nodes * 8, TPB), TPB, 0, stream>>>(rowptr, csr_src, dinv, x8, aggx, n_nodes);
  mm_tiled<8, 128, true, true><<<mm_blocks, TPB, 0, stream>>>(aggx, W1p, b1, dinv, bufP, n_nodes, 1);
  // bufP = h1s (bf16, prescaled)

  // ---- layer 2: g1(bf16) = dinv * sum ; h2(bf16) = relu(g1 @ W2 + b2) ----
  gather4_kernel<<<cdiv(n_nodes * 64, TPB), TPB, 0, stream>>>(rowptr, csr_src, dinv,
                                                              (const uint4*)bufP, (uint4*)bufQ, n_nodes);
  mm_mfma<128, 128><<<mfma_blocks, TPB, 0, stream>>>((const unsigned short*)bufQ, W2T, b2,
                                                     (unsigned short*)bufP, n_nodes, 1);
  // bufP = h2 (bf16)

  // ---- encoder fc: z(bf16) = h2 @ Wfc + bfc ----
  mm_mfma<128, 64><<<mfma_blocks, TPB, 0, stream>>>((const unsigned short*)bufP, WfcT, bfc,
                                                    (unsigned short*)bufR, n_nodes, 0);
  // bufR = z (bf16)

  // ---- decoder tables (bf16): atab = z@Wd1_top + bd1 ; btab = z@Wd1_bot ----
  unsigned short* atab = (unsigned short*)bufQ;
  unsigned short* btab = (unsigned short*)bufP;
  mm_mfma<64, 128><<<mfma_blocks, TPB, 0, stream>>>((const unsigned short*)bufR, Wd1aT, bd1,
                                                    atab, n_nodes, 0);
  mm_mfma<64, 128><<<mfma_blocks, TPB, 0, stream>>>((const unsigned short*)bufR, Wd1bT, nullptr,
                                                    btab, n_nodes, 0);

  // ---- per-query decode (MFMA) ----
  decoder_mfma_kernel<<<2048, TPB, 0, stream>>>(q_src, q_dst, atab, btab, Wd2, bd2, Wd3, bd3, out, n_query);
}

// Round 10
// 306.038 us; speedup vs baseline: 2.0871x; 1.0444x over previous
//
#include <hip/hip_runtime.h>
#include <hip/hip_bf16.h>
#include <cstdint>
#include <cstddef>

constexpr int TPB = 256;
constexpr int SCAN_B = 1024;
constexpr int NB   = 128;      // buckets for CSR build
constexpr int BSH  = 10;       // nodes per bucket = 1024
constexpr int NPB  = 1 << BSH;
constexpr int EPB  = 4096;     // edges per block in bucket passes
using bf16x8 = __attribute__((ext_vector_type(8))) short;
using f32x4  = __attribute__((ext_vector_type(4))) float;

static inline int cdiv(int a, int b) { return (a + b - 1) / b; }

__device__ __forceinline__ float bf2f(short u) {
  return __uint_as_float(((unsigned int)(unsigned short)u) << 16);
}
__device__ __forceinline__ short f2bf(float f) {  // RNE
  unsigned int u = __float_as_uint(f);
  return (short)((u + 0x7FFF + ((u >> 16) & 1)) >> 16);
}

// ---------- CSR build: zero global atomics ----------

__global__ __launch_bounds__(256)
void bucket_hist_kernel(const int* __restrict__ dst, int* __restrict__ bh,
                        int e_cnt, int n_blk) {
  __shared__ int h[NB];
  int tid = threadIdx.x;
  if (tid < NB) h[tid] = 0;
  __syncthreads();
  int base = blockIdx.x * EPB;
  for (int i = tid; i < EPB; i += TPB) {
    int e = base + i;
    if (e < e_cnt) atomicAdd(&h[dst[e] >> BSH], 1);
  }
  __syncthreads();
  if (tid < NB) bh[tid * n_blk + blockIdx.x] = h[tid];
}

__global__ __launch_bounds__(SCAN_B)
void scan_block_kernel(const int* __restrict__ counts, int* __restrict__ rowptr,
                       int* __restrict__ bsum, int n) {
  __shared__ int wsum[16];
  const int tid = threadIdx.x;
  const int i = blockIdx.x * SCAN_B + tid;
  const int lane = tid & 63;
  const int w = tid >> 6;
  int v = (i < n) ? counts[i] : 0;
  int s = v;
  #pragma unroll
  for (int off = 1; off < 64; off <<= 1) {
    int t = __shfl_up(s, off, 64);
    if (lane >= off) s += t;
  }
  if (lane == 63) wsum[w] = s;
  __syncthreads();
  if (tid < 16) {
    int ws_ = wsum[tid];
    #pragma unroll
    for (int off = 1; off < 16; off <<= 1) {
      int t = __shfl_up(ws_, off, 64);
      if (tid >= off) ws_ += t;
    }
    wsum[tid] = ws_;
  }
  __syncthreads();
  int woff = (w == 0) ? 0 : wsum[w - 1];
  if (i < n) rowptr[i] = woff + s - v;
  if (tid == SCAN_B - 1) bsum[blockIdx.x] = woff + s;
}

// merged carry-scan + offset-add: every block redundantly scans bsum (nb<=128) in LDS
__global__ __launch_bounds__(256)
void scan_fin_kernel(int* __restrict__ rowptr, const int* __restrict__ bsum,
                     int nb, int n, int total) {
  __shared__ int sb[128];
  int tid = threadIdx.x;
  if (tid == 0) {
    int run = 0;
    for (int b = 0; b < nb; ++b) { sb[b] = run; run += bsum[b]; }
  }
  __syncthreads();
  int i = blockIdx.x * TPB + tid;
  if (i < n) rowptr[i] += sb[i / SCAN_B];
  if (i == 0) rowptr[n] = total;
}

__global__ __launch_bounds__(256)
void bucket_scatter_kernel(const int* __restrict__ src, const int* __restrict__ dst,
                           const int* __restrict__ eoff, unsigned int* __restrict__ ebuf,
                           int e_cnt, int n_blk) {
  __shared__ int cur[NB];
  int tid = threadIdx.x;
  if (tid < NB) cur[tid] = eoff[tid * n_blk + blockIdx.x];
  __syncthreads();
  int base = blockIdx.x * EPB;
  for (int i = tid; i < EPB; i += TPB) {
    int e = base + i;
    if (e < e_cnt) {
      int d = dst[e];
      int b = d >> BSH;
      int pos = atomicAdd(&cur[b], 1);  // LDS atomic
      ebuf[pos] = ((unsigned int)src[e] << BSH) | (unsigned int)(d & (NPB - 1));
    }
  }
}

// per-bucket node hist + dinv, no global atomics
__global__ __launch_bounds__(256)
void node_hist_kernel(const unsigned int* __restrict__ ebuf, const int* __restrict__ eoff,
                      int* __restrict__ counts, float* __restrict__ dinv,
                      int n_blk, int n_nodes) {
  __shared__ int nh[NPB];
  int b = blockIdx.x;
  for (int i = threadIdx.x; i < NPB; i += TPB) nh[i] = 0;
  __syncthreads();
  int wb = eoff[b * n_blk];
  int we = eoff[(b + 1) * n_blk];
  for (int i = wb + threadIdx.x; i < we; i += TPB)
    atomicAdd(&nh[ebuf[i] & (NPB - 1)], 1);  // LDS atomic
  __syncthreads();
  int nbase = b << BSH;
  for (int i = threadIdx.x; i < NPB; i += TPB) {
    int node = nbase + i;
    if (node < n_nodes) {
      counts[node] = nh[i];
      dinv[node] = rsqrtf((float)nh[i] + 1.0f);  // +1 self-loop
    }
  }
}

__global__ __launch_bounds__(256)
void final_scatter_kernel(const unsigned int* __restrict__ ebuf, const int* __restrict__ eoff,
                          const int* __restrict__ rowptr, int* __restrict__ csr_src,
                          int n_blk, int n_nodes) {
  __shared__ int cur[NPB];
  int b = blockIdx.x;
  int nbase = b << BSH;
  for (int i = threadIdx.x; i < NPB; i += TPB) {
    int node = nbase + i;
    cur[i] = (node < n_nodes) ? rowptr[node] : 0;
  }
  __syncthreads();
  int wb = eoff[b * n_blk];
  int we = eoff[(b + 1) * n_blk];
  for (int i = wb + threadIdx.x; i < we; i += TPB) {
    unsigned int p = ebuf[i];
    int pos = atomicAdd(&cur[p & (NPB - 1)], 1);  // LDS atomic
    csr_src[pos] = (int)(p >> BSH);
  }
}

// ---------- prep ----------

__global__ void pad_x8_kernel(const float* __restrict__ x, float* __restrict__ x8, int n) {
  int i = blockIdx.x * TPB + threadIdx.x;
  if (i >= n * 8) return;
  int node = i >> 3, f = i & 7;
  x8[i] = (f < 7) ? x[node * 7 + f] : 0.0f;
}

// one kernel: W1p pad + biases (block 0), W2T (blocks 1..64),
// combined WcaT/WcbT = (Wfc@Wd1a/b)^T bf16 (blocks 65..128)
__global__ __launch_bounds__(256)
void prep_weights_kernel(const float* __restrict__ W1, const float* __restrict__ W2,
                         const float* __restrict__ Wfc, const float* __restrict__ bfc,
                         const float* __restrict__ Wd1, const float* __restrict__ bd1,
                         float* __restrict__ W1p, unsigned short* __restrict__ W2T,
                         unsigned short* __restrict__ WcaT, unsigned short* __restrict__ WcbT,
                         float* __restrict__ bca, float* __restrict__ bcb) {
  int b = blockIdx.x;
  int tid = threadIdx.x;
  if (b == 0) {
    for (int i = tid; i < 8 * 128; i += TPB)
      W1p[i] = (i < 7 * 128) ? W1[i] : 0.0f;
    // bca[j] = bd1[j] + sum_m bfc[m]*Wd1[m][j]; bcb[j] = sum_m bfc[m]*Wd1[64+m][j]
    int j = tid & 127;
    int which = tid >> 7;
    float acc = which ? 0.0f : bd1[j];
    int mo = which ? 64 : 0;
    #pragma unroll 8
    for (int m = 0; m < 64; ++m) acc = fmaf(bfc[m], Wd1[(mo + m) * 128 + j], acc);
    if (which) bcb[j] = acc; else bca[j] = acc;
  } else if (b <= 64) {
    int idx = (b - 1) * 256 + tid;   // 16384 = W2T elems
    int n = idx >> 7, k = idx & 127;
    W2T[idx] = (unsigned short)f2bf(W2[k * 128 + n]);  // W2T[n][k] = W2[k][n]
  } else {
    int idx = (b - 65) * 256 + tid;  // 16384 combined outputs
    int j = idx >> 7, k = idx & 127;
    float accA = 0.0f, accB = 0.0f;
    #pragma unroll 8
    for (int m = 0; m < 64; ++m) {
      float w = Wfc[k * 64 + m];
      accA = fmaf(w, Wd1[m * 128 + j], accA);
      accB = fmaf(w, Wd1[(64 + m) * 128 + j], accB);
    }
    WcaT[j * 128 + k] = (unsigned short)f2bf(accA);  // [N][K]
    WcbT[j * 128 + k] = (unsigned short)f2bf(accB);
  }
}

// ---------- graph pipeline ----------

// aggx = A_hat @ x8 : 8 lanes per node, 2-chain unroll
__global__ __launch_bounds__(256)
void agg_x_kernel(const int* __restrict__ rowptr, const int* __restrict__ csr_src,
                  const float* __restrict__ dinv, const float* __restrict__ x8,
                  float* __restrict__ aggx, int n_nodes) {
  int gid = blockIdx.x * TPB + threadIdx.x;
  int node = gid >> 3;
  int f = gid & 7;
  if (node >= n_nodes) return;
  float dn = dinv[node];
  float acc0 = x8[(size_t)node * 8 + f] * dn * dn;
  float acc1 = 0.0f;
  int beg = rowptr[node], end = rowptr[node + 1];
  int i = beg;
  for (; i + 1 < end; i += 2) {
    int s0 = csr_src[i];
    int s1 = csr_src[i + 1];
    float w0 = dinv[s0] * dn;
    float w1 = dinv[s1] * dn;
    acc0 = fmaf(x8[(size_t)s0 * 8 + f], w0, acc0);
    acc1 = fmaf(x8[(size_t)s1 * 8 + f], w1, acc1);
  }
  if (i < end) {
    int s = csr_src[i];
    acc0 = fmaf(x8[(size_t)s * 8 + f], dinv[s] * dn, acc0);
  }
  aggx[(size_t)node * 8 + f] = acc0 + acc1;
}

// g1 = dinv[n] * ( h1s[n] + sum_{s in N(n)} h1s[s] ); 4 edges/wave, bf16 rows
__global__ __launch_bounds__(256)
void gather4_kernel(const int* __restrict__ rowptr, const int* __restrict__ csr_src,
                    const float* __restrict__ dinv, const uint4* __restrict__ h1s,
                    uint4* __restrict__ g1, int n_nodes) {
  int wid = (blockIdx.x * TPB + threadIdx.x) >> 6;
  if (wid >= n_nodes) return;
  int lane = threadIdx.x & 63;
  int qtr = lane >> 4;
  int l = lane & 15;
  float acc[8];
  #pragma unroll
  for (int j = 0; j < 8; ++j) acc[j] = 0.0f;
  auto addv = [&](uint4 v) {
    unsigned int u[4] = {v.x, v.y, v.z, v.w};
    #pragma unroll
    for (int p = 0; p < 4; ++p) {
      acc[2 * p]     += __uint_as_float(u[p] << 16);
      acc[2 * p + 1] += __uint_as_float(u[p] & 0xffff0000u);
    }
  };
  if (qtr == 0) addv(h1s[(size_t)wid * 16 + l]);  // self term
  int beg = rowptr[wid], end = rowptr[wid + 1];
  int i = beg + qtr;
  for (; i + 4 < end; i += 8) {
    int s0 = csr_src[i];
    int s1 = csr_src[i + 4];
    uint4 v0 = h1s[(size_t)s0 * 16 + l];
    uint4 v1 = h1s[(size_t)s1 * 16 + l];
    addv(v0);
    addv(v1);
  }
  if (i < end) addv(h1s[(size_t)csr_src[i] * 16 + l]);
  #pragma unroll
  for (int j = 0; j < 8; ++j) {
    acc[j] += __shfl_xor(acc[j], 16, 64);
    acc[j] += __shfl_xor(acc[j], 32, 64);
  }
  if (qtr == 0) {
    float dn = dinv[wid];
    unsigned int w[4];
    #pragma unroll
    for (int p = 0; p < 4; ++p) {
      unsigned int lo = (unsigned int)(unsigned short)f2bf(acc[2 * p] * dn);
      unsigned int hi = (unsigned int)(unsigned short)f2bf(acc[2 * p + 1] * dn);
      w[p] = lo | (hi << 16);
    }
    uint4 o; o.x = w[0]; o.y = w[1]; o.z = w[2]; o.w = w[3];
    g1[(size_t)wid * 16 + l] = o;
  }
}

// Register-tiled SGEMM (layer-1 only: K=8); bf16 out, scale[row] after relu
template<int K, int CO>
__global__ __launch_bounds__(256)
void mm_tiled(const float* __restrict__ in, const float* __restrict__ W,
              const float* __restrict__ bias, const float* __restrict__ scale,
              unsigned short* __restrict__ outv, int n_rows) {
  constexpr int BM = 64;
  constexpr int BK = K;
  constexpr int SS = BK + 1 + (BK & 1);
  constexpr int TM = 4;
  constexpr int TN = CO / 16;
  __shared__ float s_in[BM][SS];
  __shared__ float s_w[BK][CO];
  const int tid = threadIdx.x;
  const int base = blockIdx.x * BM;
  const int tr = tid >> 4;
  const int tc = tid & 15;

  float acc[TM][TN];
  #pragma unroll
  for (int m = 0; m < TM; ++m)
    #pragma unroll
    for (int n = 0; n < TN; ++n) acc[m][n] = 0.0f;

  {
    constexpr int F4 = BM * (BK / 4);
    #pragma unroll
    for (int t = tid; t < F4; t += TPB) {
      int r = t / (BK / 4), c4 = t % (BK / 4);
      int row = base + r;
      float4 v = make_float4(0.f, 0.f, 0.f, 0.f);
      if (row < n_rows) v = *(const float4*)(in + (size_t)row * K + c4 * 4);
      s_in[r][c4 * 4 + 0] = v.x;
      s_in[r][c4 * 4 + 1] = v.y;
      s_in[r][c4 * 4 + 2] = v.z;
      s_in[r][c4 * 4 + 3] = v.w;
    }
    constexpr int WF4 = BK * CO / 4;
    #pragma unroll
    for (int t = tid; t < WF4; t += TPB)
      *(float4*)(&s_w[0][0] + t * 4) = *(const float4*)(W + t * 4);
  }
  __syncthreads();

  #pragma unroll
  for (int kk = 0; kk < BK; ++kk) {
    float a[TM], b[TN];
    #pragma unroll
    for (int m = 0; m < TM; ++m) a[m] = s_in[tr * TM + m][kk];
    #pragma unroll
    for (int n = 0; n < TN; ++n) b[n] = s_w[kk][tc + 16 * n];
    #pragma unroll
    for (int m = 0; m < TM; ++m)
      #pragma unroll
      for (int n = 0; n < TN; ++n) acc[m][n] = fmaf(a[m], b[n], acc[m][n]);
  }

  #pragma unroll
  for (int m = 0; m < TM; ++m) {
    int row = base + tr * TM + m;
    if (row < n_rows) {
      float sc = scale[row];
      #pragma unroll
      for (int n = 0; n < TN; ++n) {
        int j = tc + 16 * n;
        float v = fmaxf(acc[m][n] + bias[j], 0.0f) * sc;
        outv[(size_t)row * CO + j] = (unsigned short)f2bf(v);
      }
    }
  }
}

// MFMA GEMM: out(bf16)[n_rows,N] = A(bf16)[n_rows,K] @ WT(bf16)[N,K]^T (+bias)(+relu)
template<int K, int N>
__global__ __launch_bounds__(256)
void mm_mfma(const unsigned short* __restrict__ A, const unsigned short* __restrict__ WT,
             const float* __restrict__ bias, unsigned short* __restrict__ out,
             int n_rows, int do_relu) {
  constexpr int KS = K / 32;
  constexpr int NT = N / 16;
  const int lane = threadIdx.x & 63;
  const int col = lane & 15;
  const int sub = lane >> 4;
  const int wid = threadIdx.x >> 6;

  bf16x8 bfrag[KS][NT];
  #pragma unroll
  for (int ks = 0; ks < KS; ++ks)
    #pragma unroll
    for (int nt = 0; nt < NT; ++nt)
      bfrag[ks][nt] = *(const bf16x8*)(WT + (size_t)(nt * 16 + col) * K + ks * 32 + sub * 8);
  float bv[NT];
  #pragma unroll
  for (int nt = 0; nt < NT; ++nt) bv[nt] = bias ? bias[nt * 16 + col] : 0.0f;

  int ntiles = (n_rows + 15) >> 4;
  int stride = gridDim.x * 4;
  for (int tile = blockIdx.x * 4 + wid; tile < ntiles; tile += stride) {
    int row_a = tile * 16 + col;
    if (row_a >= n_rows) row_a = n_rows - 1;
    bf16x8 afrag[KS];
    #pragma unroll
    for (int ks = 0; ks < KS; ++ks)
      afrag[ks] = *(const bf16x8*)(A + (size_t)row_a * K + ks * 32 + sub * 8);
    f32x4 acc[NT];
    #pragma unroll
    for (int nt = 0; nt < NT; ++nt) acc[nt] = {0.f, 0.f, 0.f, 0.f};
    #pragma unroll
    for (int ks = 0; ks < KS; ++ks)
      #pragma unroll
      for (int nt = 0; nt < NT; ++nt)
        acc[nt] = __builtin_amdgcn_mfma_f32_16x16x32_bf16(afrag[ks], bfrag[ks][nt], acc[nt], 0, 0, 0);
    #pragma unroll
    for (int r = 0; r < 4; ++r) {
      int ro = tile * 16 + sub * 4 + r;
      if (ro < n_rows) {
        #pragma unroll
        for (int nt = 0; nt < NT; ++nt) {
          float v = acc[nt][r] + bv[nt];
          if (do_relu) v = fmaxf(v, 0.0f);
          out[(size_t)ro * N + nt * 16 + col] = (unsigned short)f2bf(v);
        }
      }
    }
  }
}

// MFMA decoder: 16 queries per wave-tile. (layouts validated)
__global__ __launch_bounds__(256)
void decoder_mfma_kernel(const int* __restrict__ qsrc, const int* __restrict__ qdst,
                         const unsigned short* __restrict__ atab,
                         const unsigned short* __restrict__ btab,
                         const float* __restrict__ Wd2, const float* __restrict__ bd2,
                         const float* __restrict__ Wd3, const float* __restrict__ bd3,
                         float* __restrict__ out, int n_query) {
  const int lane = threadIdx.x & 63;
  const int col = lane & 15;
  const int sub = lane >> 4;

  bf16x8 bfrag[4][4];
  #pragma unroll
  for (int ks = 0; ks < 4; ++ks)
    #pragma unroll
    for (int nt = 0; nt < 4; ++nt) {
      bf16x8 f;
      #pragma unroll
      for (int j = 0; j < 8; ++j) {
        int k = ks * 32 + sub * 8 + j;
        int n = nt * 16 + col;
        f[j] = f2bf(Wd2[k * 64 + n]);
      }
      bfrag[ks][nt] = f;
    }
  float bd2v[4], wd3v[4];
  #pragma unroll
  for (int nt = 0; nt < 4; ++nt) {
    bd2v[nt] = bd2[nt * 16 + col];
    wd3v[nt] = Wd3[nt * 16 + col];
  }
  const float bd3s = bd3[0];

  int wave = (blockIdx.x * TPB + threadIdx.x) >> 6;
  int nwaves = gridDim.x * (TPB / 64);
  int ntiles = (n_query + 15) >> 4;
  for (int t = wave; t < ntiles; t += nwaves) {
    int qb = t << 4;
    int q = qb + col;
    if (q >= n_query) q = n_query - 1;
    int si = qsrc[q], di = qdst[q];
    const bf16x8* ar = (const bf16x8*)(atab + (size_t)si * 128);
    const bf16x8* br = (const bf16x8*)(btab + (size_t)di * 128);
    bf16x8 afrag[4];
    #pragma unroll
    for (int ks = 0; ks < 4; ++ks) {
      bf16x8 av = ar[ks * 4 + sub];
      bf16x8 bv = br[ks * 4 + sub];
      bf16x8 d;
      #pragma unroll
      for (int j = 0; j < 8; ++j)
        d[j] = f2bf(fmaxf(bf2f(av[j]) + bf2f(bv[j]), 0.0f));  // d1 = relu(a+b)
      afrag[ks] = d;
    }
    f32x4 acc[4];
    #pragma unroll
    for (int nt = 0; nt < 4; ++nt) acc[nt] = {0.f, 0.f, 0.f, 0.f};
    #pragma unroll
    for (int ks = 0; ks < 4; ++ks)
      #pragma unroll
      for (int nt = 0; nt < 4; ++nt)
        acc[nt] = __builtin_amdgcn_mfma_f32_16x16x32_bf16(afrag[ks], bfrag[ks][nt], acc[nt], 0, 0, 0);
    float part[4] = {0.f, 0.f, 0.f, 0.f};
    #pragma unroll
    for (int nt = 0; nt < 4; ++nt)
      #pragma unroll
      for (int r = 0; r < 4; ++r) {
        float v = fmaxf(acc[nt][r] + bd2v[nt], 0.0f);
        part[r] = fmaf(v, wd3v[nt], part[r]);
      }
    #pragma unroll
    for (int off = 1; off < 16; off <<= 1)
      #pragma unroll
      for (int r = 0; r < 4; ++r) part[r] += __shfl_xor(part[r], off, 64);
    if (col == 0) {
      int row0 = qb + sub * 4;
      #pragma unroll
      for (int r = 0; r < 4; ++r) {
        int qq = row0 + r;
        if (qq < n_query) out[qq] = 1.0f / (1.0f + __expf(-(part[r] + bd3s)));
      }
    }
  }
}

extern "C" void kernel_launch(void* const* d_in, const int* in_sizes, int n_in,
                              void* d_out, int out_size, void* d_ws, size_t ws_size,
                              hipStream_t stream) {
  const float* x    = (const float*)d_in[0];
  const int*   ei   = (const int*)d_in[1];
  const int*   qe   = (const int*)d_in[2];
  const float* W1   = (const float*)d_in[3];
  const float* b1   = (const float*)d_in[4];
  const float* W2   = (const float*)d_in[5];
  const float* b2   = (const float*)d_in[6];
  const float* Wfc  = (const float*)d_in[7];
  const float* bfc  = (const float*)d_in[8];
  const float* Wd1  = (const float*)d_in[9];
  const float* bd1  = (const float*)d_in[10];
  const float* Wd2  = (const float*)d_in[11];
  const float* bd2  = (const float*)d_in[12];
  const float* Wd3  = (const float*)d_in[13];
  const float* bd3  = (const float*)d_in[14];
  float* out = (float*)d_out;

  const int n_nodes = in_sizes[0] / 7;
  const int n_edges = in_sizes[1] / 2;
  const int n_query = in_sizes[2] / 2;
  const int* e_src = ei;
  const int* e_dst = ei + n_edges;
  const int* q_src = qe;
  const int* q_dst = qe + n_query;

  const int n_blk1 = cdiv(n_edges, EPB);
  const int bh_len = NB * n_blk1;
  const int n_bucket = cdiv(n_nodes, NPB);

  // ---- workspace layout ----
  char* wp = (char*)d_ws;
  auto take = [&](size_t bytes) { char* p = wp; wp += (bytes + 255) & ~size_t(255); return p; };
  float* dinv    = (float*)take((size_t)n_nodes * 4);
  int*   counts  = (int*)  take((size_t)n_nodes * 4);
  int*   rowptr  = (int*)  take((size_t)(n_nodes + 1) * 4);
  int*   bsum    = (int*)  take(512 * 4);
  int*   bh      = (int*)  take((size_t)(bh_len + 1) * 4);
  int*   eoff    = (int*)  take((size_t)(bh_len + 1) * 4);
  unsigned int* ebuf = (unsigned int*)take((size_t)n_edges * 4);
  int*   csr_src = (int*)  take((size_t)n_edges * 4);
  float* x8      = (float*)take((size_t)n_nodes * 8 * 4);
  float* aggx    = (float*)take((size_t)n_nodes * 8 * 4);
  float* W1p     = (float*)take(8 * 128 * 4);
  unsigned short* W2T   = (unsigned short*)take(128 * 128 * 2);
  unsigned short* WcaT  = (unsigned short*)take(128 * 128 * 2);
  unsigned short* WcbT  = (unsigned short*)take(128 * 128 * 2);
  float* bca     = (float*)take(128 * 4);
  float* bcb     = (float*)take(128 * 4);
  float* bufP    = (float*)take((size_t)n_nodes * 128 * 4);
  float* bufQ    = (float*)take((size_t)n_nodes * 128 * 4);
  float* bufR    = (float*)take((size_t)n_nodes * 64 * 4);

  const int mm_blocks = cdiv(n_nodes, 64);
  const int node_blocks = cdiv(n_nodes, TPB);
  const int scan_blocks = cdiv(n_nodes, SCAN_B);
  const int escan_blocks = cdiv(bh_len, SCAN_B);
  const int mfma_blocks = min(1024, cdiv(cdiv(n_nodes, 16), 4));

  // ---- CSR build (no global atomics): 8 dispatches ----
  bucket_hist_kernel<<<n_blk1, TPB, 0, stream>>>(e_dst, bh, n_edges, n_blk1);
  scan_block_kernel<<<escan_blocks, SCAN_B, 0, stream>>>(bh, eoff, bsum, bh_len);
  scan_fin_kernel<<<cdiv(bh_len, TPB), TPB, 0, stream>>>(eoff, bsum, escan_blocks, bh_len, n_edges);
  bucket_scatter_kernel<<<n_blk1, TPB, 0, stream>>>(e_src, e_dst, eoff, ebuf, n_edges, n_blk1);
  node_hist_kernel<<<n_bucket, TPB, 0, stream>>>(ebuf, eoff, counts, dinv, n_blk1, n_nodes);
  scan_block_kernel<<<scan_blocks, SCAN_B, 0, stream>>>(counts, rowptr, bsum, n_nodes);
  scan_fin_kernel<<<node_blocks, TPB, 0, stream>>>(rowptr, bsum, scan_blocks, n_nodes, n_edges);
  final_scatter_kernel<<<n_bucket, TPB, 0, stream>>>(ebuf, eoff, rowptr, csr_src, n_blk1, n_nodes);

  // ---- prep: 2 dispatches ----
  pad_x8_kernel<<<cdiv(n_nodes * 8, TPB), TPB, 0, stream>>>(x, x8, n_nodes);
  prep_weights_kernel<<<129, TPB, 0, stream>>>(W1, W2, Wfc, bfc, Wd1, bd1,
                                               W1p, W2T, WcaT, WcbT, bca, bcb);

  // ---- layer 1: aggx = A_hat x ; h1s(bf16) = relu(aggx @ W1p + b1) * dinv ----
  agg_x_kernel<<<cdiv(n_nodes * 8, TPB), TPB, 0, stream>>>(rowptr, csr_src, dinv, x8, aggx, n_nodes);
  mm_tiled<8, 128><<<mm_blocks, TPB, 0, stream>>>(aggx, W1p, b1, dinv, (unsigned short*)bufP, n_nodes);
  // bufP = h1s (bf16, prescaled)

  // ---- layer 2: g1(bf16) = dinv * sum ; h2(bf16) = relu(g1 @ W2 + b2) ----
  gather4_kernel<<<cdiv(n_nodes * 64, TPB), TPB, 0, stream>>>(rowptr, csr_src, dinv,
                                                              (const uint4*)bufP, (uint4*)bufQ, n_nodes);
  mm_mfma<128, 128><<<mfma_blocks, TPB, 0, stream>>>((const unsigned short*)bufQ, W2T, b2,
                                                     (unsigned short*)bufP, n_nodes, 1);
  // bufP = h2 (bf16)

  // ---- decoder tables directly from h2 (fc folded in): atab = h2@Wca + bca ; btab = h2@Wcb + bcb ----
  unsigned short* atab = (unsigned short*)bufQ;
  unsigned short* btab = (unsigned short*)bufR;
  mm_mfma<128, 128><<<mfma_blocks, TPB, 0, stream>>>((const unsigned short*)bufP, WcaT, bca,
                                                     atab, n_nodes, 0);
  mm_mfma<128, 128><<<mfma_blocks, TPB, 0, stream>>>((const unsigned short*)bufP, WcbT, bcb,
                                                     btab, n_nodes, 0);

  // ---- per-query decode (MFMA) ----
  decoder_mfma_kernel<<<2048, TPB, 0, stream>>>(q_src, q_dst, atab, btab, Wd2, bd2, Wd3, bd3, out, n_query);
}